// Round 1
// baseline (3037.198 us; speedup 1.0000x reference)
//
#include <hip/hip_runtime.h>
#include <math.h>

#define NN 20000
#define NE 200000
#define TT 13

// ---------------- instance norm (over time) + save stdev/means ----------------
__global__ __launch_bounds__(256) void k_instnorm(const float* __restrict__ x,
    float* __restrict__ xc, float* __restrict__ stdev, float* __restrict__ means){
  int n = blockIdx.x*256 + threadIdx.x;
  if(n >= NN) return;
  float v[TT]; float s = 0.f;
#pragma unroll
  for(int t=0;t<TT;t++){ v[t] = x[n*TT+t]; s += v[t]; }
  float m = s * (1.0f/TT);
  float s2 = 0.f;
#pragma unroll
  for(int t=0;t<TT;t++){ v[t] -= m; s2 += v[t]*v[t]; }
  float sd = sqrtf(s2*(1.0f/TT) + 1e-5f);
  float inv = 1.0f/sd;
#pragma unroll
  for(int t=0;t<TT;t++) xc[n*TT+t] = v[t]*inv;
  stdev[n] = sd; means[n] = m;
}

// ---------------- start 1x1 conv: h[n,c,t] = sW[c]*xc[n,t]+sb[c] ----------------
__global__ __launch_bounds__(256) void k_start(const float* __restrict__ xc,
    const float* __restrict__ sW, const float* __restrict__ sb, float* __restrict__ h){
  int idx = blockIdx.x*256 + threadIdx.x;
  if(idx >= NN*32*TT) return;
  int t = idx % TT; int c = (idx/TT) & 31; int n = idx/(TT*32);
  h[idx] = sW[c]*xc[n*TT+t] + sb[c];
}

// ---------------- GCN edge-norm precompute ----------------
__global__ __launch_bounds__(256) void k_deg(const int* __restrict__ ei,
    const float* __restrict__ ea, float* __restrict__ deg){
  int e = blockIdx.x*256 + threadIdx.x;
  if(e >= NE) return;
  int r = ei[e], c = ei[NE+e];
  float w = (r==c) ? 0.f : ea[e];
  if(w != 0.f) atomicAdd(&deg[r], w);
}

__global__ __launch_bounds__(256) void k_dinv(float* __restrict__ deg){
  int n = blockIdx.x*256 + threadIdx.x;
  if(n >= NN) return;
  float d = deg[n];
  deg[n] = (d > 0.f) ? rsqrtf(d) : 0.f;
}

__global__ __launch_bounds__(256) void k_norm(const int* __restrict__ ei,
    const float* __restrict__ ea, const float* __restrict__ dinv, float* __restrict__ nrm){
  int e = blockIdx.x*256 + threadIdx.x;
  if(e >= NE) return;
  int r = ei[e], c = ei[NE+e];
  float w = (r==c) ? 0.f : ea[e];
  nrm[e] = dinv[r]*w*dinv[c];
}

// ---------------- scatter: tx1[col] -= norm*h[row]  (per edge, 4 feats/thread) ----------------
__global__ __launch_bounds__(256) void k_scatter(const float* __restrict__ h,
    const int* __restrict__ ei, const float* __restrict__ nrm,
    float* __restrict__ tx1, int F, int q){
  int idx = blockIdx.x*256 + threadIdx.x;
  if(idx >= NE*q) return;
  int e = idx / q; int f4 = (idx - e*q)*4;
  float nv = nrm[e];
  if(nv == 0.f) return;
  int r = ei[e], c = ei[NE+e];
  const float4 hv = *reinterpret_cast<const float4*>(&h[(size_t)r*F + f4]);
  float* dst = &tx1[(size_t)c*F + f4];
  atomicAdd(dst+0, -nv*hv.x);
  atomicAdd(dst+1, -nv*hv.y);
  atomicAdd(dst+2, -nv*hv.z);
  atomicAdd(dst+3, -nv*hv.w);
}

// ---------------- tiled fp32 GEMM:  C = A1@B1 (+ A2@B2) + bias ----------------
// A:[M,K] rm, B:[K,N] rm, bias:[N].  64x64 tile, 256 thr, 4x4/thread. K%16==0, N%64==0.
template<bool DUAL>
__global__ __launch_bounds__(256) void k_gemm(
    const float* __restrict__ A1, const float* __restrict__ B1,
    const float* __restrict__ A2, const float* __restrict__ B2,
    const float* __restrict__ bias, float* __restrict__ C,
    int M, int N, int K){
  __shared__ float As1[16][64];
  __shared__ float Bs1[16][64];
  __shared__ float As2[DUAL?16:1][64];
  __shared__ float Bs2[DUAL?16:1][64];
  int tid = threadIdx.x;
  int tx = tid & 15, ty = tid >> 4;
  int m0 = blockIdx.x*64, n0 = blockIdx.y*64;
  int alr = tid >> 2;           // 0..63  (A row in tile)
  int alk = (tid & 3)*4;        // k quad
  int blr = tid >> 4;           // 0..15  (B row in tile)
  int bln = (tid & 15)*4;       // n quad
  float acc[4][4] = {};
  bool aval = (m0 + alr) < M;
  const float* Ar1 = A1 + (size_t)(m0+alr)*K;
  const float* Ar2 = DUAL ? (A2 + (size_t)(m0+alr)*K) : A1;
  for(int k0 = 0; k0 < K; k0 += 16){
    float4 a1 = make_float4(0,0,0,0), a2 = make_float4(0,0,0,0);
    if(aval){
      a1 = *reinterpret_cast<const float4*>(Ar1 + k0 + alk);
      if(DUAL) a2 = *reinterpret_cast<const float4*>(Ar2 + k0 + alk);
    }
    float4 b1 = *reinterpret_cast<const float4*>(&B1[(size_t)(k0+blr)*N + n0 + bln]);
    float4 b2 = make_float4(0,0,0,0);
    if(DUAL) b2 = *reinterpret_cast<const float4*>(&B2[(size_t)(k0+blr)*N + n0 + bln]);
    __syncthreads();
    As1[alk+0][alr]=a1.x; As1[alk+1][alr]=a1.y; As1[alk+2][alr]=a1.z; As1[alk+3][alr]=a1.w;
    *reinterpret_cast<float4*>(&Bs1[blr][bln]) = b1;
    if(DUAL){
      As2[alk+0][alr]=a2.x; As2[alk+1][alr]=a2.y; As2[alk+2][alr]=a2.z; As2[alk+3][alr]=a2.w;
      *reinterpret_cast<float4*>(&Bs2[blr][bln]) = b2;
    }
    __syncthreads();
#pragma unroll
    for(int kk = 0; kk < 16; kk++){
      float4 av1 = *reinterpret_cast<const float4*>(&As1[kk][ty*4]);
      float4 bv1 = *reinterpret_cast<const float4*>(&Bs1[kk][tx*4]);
      float av[4] = {av1.x, av1.y, av1.z, av1.w};
      float bv[4] = {bv1.x, bv1.y, bv1.z, bv1.w};
#pragma unroll
      for(int i=0;i<4;i++)
#pragma unroll
        for(int j=0;j<4;j++) acc[i][j] += av[i]*bv[j];
      if(DUAL){
        float4 av2 = *reinterpret_cast<const float4*>(&As2[kk][ty*4]);
        float4 bv2 = *reinterpret_cast<const float4*>(&Bs2[kk][tx*4]);
        float a2r[4] = {av2.x, av2.y, av2.z, av2.w};
        float b2r[4] = {bv2.x, bv2.y, bv2.z, bv2.w};
#pragma unroll
        for(int i=0;i<4;i++)
#pragma unroll
          for(int j=0;j<4;j++) acc[i][j] += a2r[i]*b2r[j];
      }
    }
  }
  float4 bv = *reinterpret_cast<const float4*>(&bias[n0 + tx*4]);
#pragma unroll
  for(int i=0;i<4;i++){
    int m = m0 + ty*4 + i;
    if(m < M){
      float4 o;
      o.x = acc[i][0] + bv.x; o.y = acc[i][1] + bv.y;
      o.z = acc[i][2] + bv.z; o.w = acc[i][3] + bv.w;
      *reinterpret_cast<float4*>(&C[(size_t)m*N + n0 + tx*4]) = o;
    }
  }
}

// ---------------- gated dilated conv + residual; also emit gated last-col ----------------
__global__ __launch_bounds__(256) void k_gated(
    const float* __restrict__ hIn, float* __restrict__ hOut, float* __restrict__ gl,
    const float* __restrict__ fW, const float* __restrict__ fb,
    const float* __restrict__ gW, const float* __restrict__ gb,
    int layer, int d, int Tin, int Tout){
  __shared__ float fw0[1024], fw1[1024], gw0[1024], gw1[1024];
  __shared__ float fbs[32], gbs[32];
  int tid = threadIdx.x;
  const float* fWb = fW + layer*2048;
  const float* gWb = gW + layer*2048;
  for(int j = tid; j < 1024; j += 256){
    int k = j >> 5, c = j & 31;            // store [k][c] -> bank = c
    fw0[k*32+c] = fWb[c*64 + k*2];
    fw1[k*32+c] = fWb[c*64 + k*2 + 1];
    gw0[k*32+c] = gWb[c*64 + k*2];
    gw1[k*32+c] = gWb[c*64 + k*2 + 1];
  }
  if(tid < 32){ fbs[tid] = fb[layer*32+tid]; gbs[tid] = gb[layer*32+tid]; }
  __syncthreads();
  int total = NN*32*Tout;
  for(int idx = blockIdx.x*256 + tid; idx < total; idx += gridDim.x*256){
    int t = idx % Tout; int rem = idx / Tout; int c = rem & 31; int n = rem >> 5;
    const float* hn = hIn + (size_t)n*32*Tin;
    float fa = fbs[c], ga = gbs[c];
#pragma unroll 8
    for(int k = 0; k < 32; k++){
      float h0 = hn[k*Tin + t];
      float h1 = hn[k*Tin + t + d];
      fa += fw0[k*32+c]*h0 + fw1[k*32+c]*h1;
      ga += gw0[k*32+c]*h0 + gw1[k*32+c]*h1;
    }
    float gated = tanhf(fa) * (1.0f/(1.0f + __expf(-ga)));
    float outv = gated + hn[c*Tin + t + d];
    hOut[idx] = outv;
    if(t == Tout-1) gl[(size_t)n*256 + c] = gated;   // gl already offset by layer*32
  }
}

// ---------------- batchnorm: reduce then apply ----------------
__global__ __launch_bounds__(256) void k_bn_reduce(const float* __restrict__ h,
    int Tout, float* __restrict__ bn){
  int c = blockIdx.y;
  int tid = threadIdx.x;
  int count = NN * Tout;
  float s = 0.f, s2 = 0.f;
  for(int i = blockIdx.x*256 + tid; i < count; i += gridDim.x*256){
    int n = i / Tout, t = i - n*Tout;
    float v = h[((size_t)n*32 + c)*Tout + t];
    s += v; s2 += v*v;
  }
  __shared__ float rs[256], rs2[256];
  rs[tid] = s; rs2[tid] = s2; __syncthreads();
  for(int off = 128; off > 0; off >>= 1){
    if(tid < off){ rs[tid] += rs[tid+off]; rs2[tid] += rs2[tid+off]; }
    __syncthreads();
  }
  if(tid == 0){ atomicAdd(&bn[c], rs[0]); atomicAdd(&bn[32+c], rs2[0]); }
}

__global__ __launch_bounds__(256) void k_bn_apply(float* __restrict__ h,
    int Tout, const float* __restrict__ bn){
  int idx = blockIdx.x*256 + threadIdx.x;
  int total = NN*32*Tout;
  if(idx >= total) return;
  int c = (idx / Tout) & 31;
  float cnt = (float)(NN*Tout);
  float m = bn[c] / cnt;
  float v = bn[32+c] / cnt - m*m;
  h[idx] = (h[idx] - m) * rsqrtf(v + 1e-5f);
}

// ---------------- prep: skip weight re-layout Bw[(i*32+c)*256+s]=skip_W[i][s][c]; bias2=sum_i sb ----------------
__global__ __launch_bounds__(256) void k_prep(const float* __restrict__ sW,
    const float* __restrict__ sb, float* __restrict__ Bw, float* __restrict__ b2){
  int idx = blockIdx.x*256 + threadIdx.x;
  if(idx >= 65536) return;
  int s = idx & 255; int ic = idx >> 8; int i = ic >> 5; int c = ic & 31;
  Bw[idx] = sW[i*8192 + s*32 + c];
  if(idx < 256){
    float acc = 0.f;
    for(int l = 0; l < 8; l++) acc += sb[l*256 + idx];
    b2[idx] = acc;
  }
}

// ---------------- fold end2@end1 into Wc[12,256], bc[12] ----------------
__global__ __launch_bounds__(256) void k_comb(const float* __restrict__ e1W,
    const float* __restrict__ e1b, const float* __restrict__ e2W,
    const float* __restrict__ e2b, float* __restrict__ Wc, float* __restrict__ bc){
  int idx = blockIdx.x*256 + threadIdx.x;
  if(idx >= 12*256) return;
  int k = idx >> 8, c = idx & 255;
  float acc = 0.f;
  for(int o = 0; o < 512; o++) acc += e2W[k*512+o]*e1W[o*256+c];
  Wc[idx] = acc;
  if(c == 0){
    float b = e2b[k];
    for(int o = 0; o < 512; o++) b += e2W[k*512+o]*e1b[o];
    bc[k] = b;
  }
}

// ---------------- final: out[n,k] = (Wc@relu(skip[n,:]) + bc)*stdev[n]+means[n] ----------------
__global__ __launch_bounds__(256) void k_final(const float* __restrict__ skip,
    const float* __restrict__ Wc, const float* __restrict__ bc,
    const float* __restrict__ stdev, const float* __restrict__ means,
    float* __restrict__ out){
  __shared__ float w[3072];
  __shared__ float bcs[12];
  int tid = threadIdx.x;
  for(int j = tid; j < 3072; j += 256){
    int c = j / 12, k = j - c*12;
    w[c*12 + k] = Wc[k*256 + c];
  }
  if(tid < 12) bcs[tid] = bc[tid];
  __syncthreads();
  int idx = blockIdx.x*256 + tid;
  if(idx >= NN*12) return;
  int n = idx / 12, k = idx - n*12;
  const float* sr = skip + (size_t)n*256;
  float acc = bcs[k];
#pragma unroll 8
  for(int c = 0; c < 256; c++) acc += w[c*12 + k]*fmaxf(sr[c], 0.f);
  out[idx] = acc*stdev[n] + means[n];
}

extern "C" void kernel_launch(void* const* d_in, const int* in_sizes, int n_in,
                              void* d_out, int out_size, void* d_ws, size_t ws_size,
                              hipStream_t stream) {
  const float* x      = (const float*)d_in[0];
  const int*   ei     = (const int*)  d_in[1];
  const float* ea     = (const float*)d_in[2];
  const float* startW = (const float*)d_in[3];
  const float* startb = (const float*)d_in[4];
  const float* fW     = (const float*)d_in[5];
  const float* fb     = (const float*)d_in[6];
  const float* gW     = (const float*)d_in[7];
  const float* gb     = (const float*)d_in[8];
  const float* sW     = (const float*)d_in[9];
  const float* sb     = (const float*)d_in[10];
  const float* g0W0   = (const float*)d_in[11];
  const float* g0W1   = (const float*)d_in[12];
  const float* g0b    = (const float*)d_in[13];
  const float* g1W0   = (const float*)d_in[14];
  const float* g1W1   = (const float*)d_in[15];
  const float* g1b    = (const float*)d_in[16];
  const float* e1W    = (const float*)d_in[17];
  const float* e1b    = (const float*)d_in[18];
  const float* e2W    = (const float*)d_in[19];
  const float* e2b    = (const float*)d_in[20];
  float* out = (float*)d_out;
  float* ws  = (float*)d_ws;

  size_t o = 0;
  float* hA    = ws + o; o += (size_t)NN*32*TT;
  float* hB    = ws + o; o += (size_t)NN*32*TT;
  float* glall = ws + o; o += (size_t)NN*256;
  float* stdev = ws + o; o += NN;
  float* means = ws + o; o += NN;
  float* deg   = ws + o; o += NN;
  float* bn    = ws + o; o += 64;
  float* normb = ws + o; o += NE;
  float* xc    = ws + o; o += (size_t)NN*TT;
  float* Bw    = ws + o; o += 256*256;
  float* bias2 = ws + o; o += 256;
  float* Wc    = ws + o; o += 12*256;
  float* bc    = ws + o; o += 16;
  float* tx1   = ws + o; o += (size_t)NN*384;   // doubles as skip buffer at the end

  hipMemsetAsync(deg, 0, NN*sizeof(float), stream);
  k_instnorm<<<(NN+255)/256, 256, 0, stream>>>(x, xc, stdev, means);
  k_start<<<((NN*32*TT)+255)/256, 256, 0, stream>>>(xc, startW, startb, hA);
  k_deg<<<(NE+255)/256, 256, 0, stream>>>(ei, ea, deg);
  k_dinv<<<(NN+255)/256, 256, 0, stream>>>(deg);
  k_norm<<<(NE+255)/256, 256, 0, stream>>>(ei, ea, deg, normb);
  k_prep<<<256, 256, 0, stream>>>(sW, sb, Bw, bias2);
  k_comb<<<12, 256, 0, stream>>>(e1W, e1b, e2W, e2b, Wc, bc);

  float* cur = hA; float* alt = hB;
  int T = TT;
  const int dil[8] = {1,2,1,2,1,2,1,2};
  for(int i = 0; i < 8; i++){
    int d = dil[i];
    if(i == 1 || i == 5){
      int F = 32*T;
      const float* W0 = (i==1) ? g0W0 : g1W0;
      const float* W1 = (i==1) ? g0W1 : g1W1;
      const float* bb = (i==1) ? g0b  : g1b;
      hipMemsetAsync(tx1, 0, (size_t)NN*F*sizeof(float), stream);
      int q = F/4;
      int nthr = NE*q;
      k_scatter<<<(nthr+255)/256, 256, 0, stream>>>(cur, ei, normb, tx1, F, q);
      dim3 gg((NN+63)/64, F/64);
      k_gemm<true><<<gg, 256, 0, stream>>>(cur, W0, tx1, W1, bb, alt, NN, F, F);
      float* tmp = cur; cur = alt; alt = tmp;
    }
    int Tout = T - d;
    hipMemsetAsync(bn, 0, 64*sizeof(float), stream);
    k_gated<<<2048, 256, 0, stream>>>(cur, alt, glall + i*32, fW, fb, gW, gb, i, d, T, Tout);
    dim3 gbn(32, 32);
    k_bn_reduce<<<gbn, 256, 0, stream>>>(alt, Tout, bn);
    k_bn_apply<<<((NN*32*Tout)+255)/256, 256, 0, stream>>>(alt, Tout, bn);
    float* tmp = cur; cur = alt; alt = tmp;
    T = Tout;
  }

  // skip = glall @ Bw + bias2   (tx1 buffer reused as [N,256] skip)
  float* skipb = tx1;
  dim3 gs((NN+63)/64, 256/64);
  k_gemm<false><<<gs, 256, 0, stream>>>(glall, Bw, nullptr, nullptr, bias2, skipb, NN, 256, 256);
  k_final<<<((NN*12)+255)/256, 256, 0, stream>>>(skipb, Wc, bc, stdev, means, out);
}

// Round 2
// 1698.254 us; speedup vs baseline: 1.7884x; 1.7884x over previous
//
#include <hip/hip_runtime.h>
#include <math.h>

#define NN 20000
#define NE 200000
#define TT 13

// ---------------- instance norm (over time) + save stdev/means ----------------
__global__ __launch_bounds__(256) void k_instnorm(const float* __restrict__ x,
    float* __restrict__ xc, float* __restrict__ stdev, float* __restrict__ means){
  int n = blockIdx.x*256 + threadIdx.x;
  if(n >= NN) return;
  float v[TT]; float s = 0.f;
#pragma unroll
  for(int t=0;t<TT;t++){ v[t] = x[n*TT+t]; s += v[t]; }
  float m = s * (1.0f/TT);
  float s2 = 0.f;
#pragma unroll
  for(int t=0;t<TT;t++){ v[t] -= m; s2 += v[t]*v[t]; }
  float sd = sqrtf(s2*(1.0f/TT) + 1e-5f);
  float inv = 1.0f/sd;
#pragma unroll
  for(int t=0;t<TT;t++) xc[n*TT+t] = v[t]*inv;
  stdev[n] = sd; means[n] = m;
}

// ---------------- start 1x1 conv: h[n,c,t] = sW[c]*xc[n,t]+sb[c] ----------------
__global__ __launch_bounds__(256) void k_start(const float* __restrict__ xc,
    const float* __restrict__ sW, const float* __restrict__ sb, float* __restrict__ h){
  int idx = blockIdx.x*256 + threadIdx.x;
  if(idx >= NN*32*TT) return;
  int t = idx % TT; int c = (idx/TT) & 31; int n = idx/(TT*32);
  h[idx] = sW[c]*xc[n*TT+t] + sb[c];
}

// ---------------- GCN edge-norm precompute ----------------
__global__ __launch_bounds__(256) void k_deg(const int* __restrict__ ei,
    const float* __restrict__ ea, float* __restrict__ deg){
  int e = blockIdx.x*256 + threadIdx.x;
  if(e >= NE) return;
  int r = ei[e], c = ei[NE+e];
  float w = (r==c) ? 0.f : ea[e];
  if(w != 0.f) atomicAdd(&deg[r], w);
}

__global__ __launch_bounds__(256) void k_dinv(float* __restrict__ deg){
  int n = blockIdx.x*256 + threadIdx.x;
  if(n >= NN) return;
  float d = deg[n];
  deg[n] = (d > 0.f) ? rsqrtf(d) : 0.f;
}

__global__ __launch_bounds__(256) void k_norm(const int* __restrict__ ei,
    const float* __restrict__ ea, const float* __restrict__ dinv, float* __restrict__ nrm){
  int e = blockIdx.x*256 + threadIdx.x;
  if(e >= NE) return;
  int r = ei[e], c = ei[NE+e];
  float w = (r==c) ? 0.f : ea[e];
  nrm[e] = dinv[r]*w*dinv[c];
}

// ---------------- CSR build: count -> scan -> place ----------------
__global__ __launch_bounds__(256) void k_count(const float* __restrict__ nrm,
    const int* __restrict__ ei, int* __restrict__ cnt){
  int e = blockIdx.x*256 + threadIdx.x;
  if(e >= NE) return;
  if(nrm[e] != 0.f) atomicAdd(&cnt[ei[NE+e]], 1);
}

__global__ __launch_bounds__(1024) void k_scan(const int* __restrict__ cnt,
    int* __restrict__ rowptr){
  __shared__ int buf[1024];
  __shared__ int carry;
  int tid = threadIdx.x;
  if(tid == 0) carry = 0;
  __syncthreads();
  for(int base = 0; base < NN; base += 1024){
    int i = base + tid;
    int v = (i < NN) ? cnt[i] : 0;
    buf[tid] = v; __syncthreads();
    for(int off = 1; off < 1024; off <<= 1){
      int t = (tid >= off) ? buf[tid-off] : 0;
      __syncthreads();
      buf[tid] += t;
      __syncthreads();
    }
    if(i < NN) rowptr[i] = carry + buf[tid] - v;
    __syncthreads();
    if(tid == 1023) carry += buf[1023];
    __syncthreads();
  }
  if(tid == 0) rowptr[NN] = carry;
}

__global__ __launch_bounds__(256) void k_place(const float* __restrict__ nrm,
    const int* __restrict__ ei, int* __restrict__ woff,
    int* __restrict__ rowArr, float* __restrict__ nrmArr){
  int e = blockIdx.x*256 + threadIdx.x;
  if(e >= NE) return;
  float nv = nrm[e];
  if(nv == 0.f) return;
  int c = ei[NE+e];
  int pos = atomicAdd(&woff[c], 1);
  rowArr[pos] = ei[e];
  nrmArr[pos] = nv;
}

// ---------------- gather SpMM: tx1[node,f] = -sum_e nrm[e]*h[row[e],f] ----------------
// launched with <<<NN, F>>>, F in {384,192}
__global__ void k_gather(const float* __restrict__ h, const int* __restrict__ rowArr,
    const float* __restrict__ nrmArr, const int* __restrict__ rowptr,
    float* __restrict__ tx1, int F){
  int node = blockIdx.x;
  int f = threadIdx.x;
  int beg = rowptr[node], end = rowptr[node+1];
  __shared__ int srow[64];
  __shared__ float snrm[64];
  float acc = 0.f;
  for(int base = beg; base < end; base += 64){
    int m = end - base; if(m > 64) m = 64;
    __syncthreads();
    if(f < m){ srow[f] = rowArr[base+f]; snrm[f] = nrmArr[base+f]; }
    __syncthreads();
    for(int j = 0; j < m; j++)
      acc += snrm[j]*h[(size_t)srow[j]*F + f];
  }
  tx1[(size_t)node*F + f] = -acc;
}

// ---------------- tiled fp32 GEMM:  C = A1@B1 (+ A2@B2) + bias ----------------
template<bool DUAL>
__global__ __launch_bounds__(256) void k_gemm(
    const float* __restrict__ A1, const float* __restrict__ B1,
    const float* __restrict__ A2, const float* __restrict__ B2,
    const float* __restrict__ bias, float* __restrict__ C,
    int M, int N, int K){
  __shared__ float As1[16][64];
  __shared__ float Bs1[16][64];
  __shared__ float As2[DUAL?16:1][64];
  __shared__ float Bs2[DUAL?16:1][64];
  int tid = threadIdx.x;
  int tx = tid & 15, ty = tid >> 4;
  int m0 = blockIdx.x*64, n0 = blockIdx.y*64;
  int alr = tid >> 2;
  int alk = (tid & 3)*4;
  int blr = tid >> 4;
  int bln = (tid & 15)*4;
  float acc[4][4] = {};
  bool aval = (m0 + alr) < M;
  const float* Ar1 = A1 + (size_t)(m0+alr)*K;
  const float* Ar2 = DUAL ? (A2 + (size_t)(m0+alr)*K) : A1;
  for(int k0 = 0; k0 < K; k0 += 16){
    float4 a1 = make_float4(0,0,0,0), a2 = make_float4(0,0,0,0);
    if(aval){
      a1 = *reinterpret_cast<const float4*>(Ar1 + k0 + alk);
      if(DUAL) a2 = *reinterpret_cast<const float4*>(Ar2 + k0 + alk);
    }
    float4 b1 = *reinterpret_cast<const float4*>(&B1[(size_t)(k0+blr)*N + n0 + bln]);
    float4 b2 = make_float4(0,0,0,0);
    if(DUAL) b2 = *reinterpret_cast<const float4*>(&B2[(size_t)(k0+blr)*N + n0 + bln]);
    __syncthreads();
    As1[alk+0][alr]=a1.x; As1[alk+1][alr]=a1.y; As1[alk+2][alr]=a1.z; As1[alk+3][alr]=a1.w;
    *reinterpret_cast<float4*>(&Bs1[blr][bln]) = b1;
    if(DUAL){
      As2[alk+0][alr]=a2.x; As2[alk+1][alr]=a2.y; As2[alk+2][alr]=a2.z; As2[alk+3][alr]=a2.w;
      *reinterpret_cast<float4*>(&Bs2[blr][bln]) = b2;
    }
    __syncthreads();
#pragma unroll
    for(int kk = 0; kk < 16; kk++){
      float4 av1 = *reinterpret_cast<const float4*>(&As1[kk][ty*4]);
      float4 bv1 = *reinterpret_cast<const float4*>(&Bs1[kk][tx*4]);
      float av[4] = {av1.x, av1.y, av1.z, av1.w};
      float bv[4] = {bv1.x, bv1.y, bv1.z, bv1.w};
#pragma unroll
      for(int i=0;i<4;i++)
#pragma unroll
        for(int j=0;j<4;j++) acc[i][j] += av[i]*bv[j];
      if(DUAL){
        float4 av2 = *reinterpret_cast<const float4*>(&As2[kk][ty*4]);
        float4 bv2 = *reinterpret_cast<const float4*>(&Bs2[kk][tx*4]);
        float a2r[4] = {av2.x, av2.y, av2.z, av2.w};
        float b2r[4] = {bv2.x, bv2.y, bv2.z, bv2.w};
#pragma unroll
        for(int i=0;i<4;i++)
#pragma unroll
          for(int j=0;j<4;j++) acc[i][j] += a2r[i]*b2r[j];
      }
    }
  }
  float4 bv = *reinterpret_cast<const float4*>(&bias[n0 + tx*4]);
#pragma unroll
  for(int i=0;i<4;i++){
    int m = m0 + ty*4 + i;
    if(m < M){
      float4 o;
      o.x = acc[i][0] + bv.x; o.y = acc[i][1] + bv.y;
      o.z = acc[i][2] + bv.z; o.w = acc[i][3] + bv.w;
      *reinterpret_cast<float4*>(&C[(size_t)m*N + n0 + tx*4]) = o;
    }
  }
}

// ---------------- gated dilated conv + residual; also emit gated last-col ----------------
__global__ __launch_bounds__(256) void k_gated(
    const float* __restrict__ hIn, float* __restrict__ hOut, float* __restrict__ gl,
    const float* __restrict__ fW, const float* __restrict__ fb,
    const float* __restrict__ gW, const float* __restrict__ gb,
    int layer, int d, int Tin, int Tout){
  __shared__ float fw0[1024], fw1[1024], gw0[1024], gw1[1024];
  __shared__ float fbs[32], gbs[32];
  int tid = threadIdx.x;
  const float* fWb = fW + layer*2048;
  const float* gWb = gW + layer*2048;
  for(int j = tid; j < 1024; j += 256){
    int k = j >> 5, c = j & 31;
    fw0[k*32+c] = fWb[c*64 + k*2];
    fw1[k*32+c] = fWb[c*64 + k*2 + 1];
    gw0[k*32+c] = gWb[c*64 + k*2];
    gw1[k*32+c] = gWb[c*64 + k*2 + 1];
  }
  if(tid < 32){ fbs[tid] = fb[layer*32+tid]; gbs[tid] = gb[layer*32+tid]; }
  __syncthreads();
  int total = NN*32*Tout;
  for(int idx = blockIdx.x*256 + tid; idx < total; idx += gridDim.x*256){
    int t = idx % Tout; int rem = idx / Tout; int c = rem & 31; int n = rem >> 5;
    const float* hn = hIn + (size_t)n*32*Tin;
    float fa = fbs[c], ga = gbs[c];
#pragma unroll 8
    for(int k = 0; k < 32; k++){
      float h0 = hn[k*Tin + t];
      float h1 = hn[k*Tin + t + d];
      fa += fw0[k*32+c]*h0 + fw1[k*32+c]*h1;
      ga += gw0[k*32+c]*h0 + gw1[k*32+c]*h1;
    }
    float gated = tanhf(fa) * (1.0f/(1.0f + __expf(-ga)));
    float outv = gated + hn[c*Tin + t + d];
    hOut[idx] = outv;
    if(t == Tout-1) gl[(size_t)n*256 + c] = gated;
  }
}

// ---------------- batchnorm: reduce then apply ----------------
__global__ __launch_bounds__(256) void k_bn_reduce(const float* __restrict__ h,
    int Tout, float* __restrict__ bn){
  int c = blockIdx.y;
  int tid = threadIdx.x;
  int count = NN * Tout;
  float s = 0.f, s2 = 0.f;
  for(int i = blockIdx.x*256 + tid; i < count; i += gridDim.x*256){
    int n = i / Tout, t = i - n*Tout;
    float v = h[((size_t)n*32 + c)*Tout + t];
    s += v; s2 += v*v;
  }
  __shared__ float rs[256], rs2[256];
  rs[tid] = s; rs2[tid] = s2; __syncthreads();
  for(int off = 128; off > 0; off >>= 1){
    if(tid < off){ rs[tid] += rs[tid+off]; rs2[tid] += rs2[tid+off]; }
    __syncthreads();
  }
  if(tid == 0){ atomicAdd(&bn[c], rs[0]); atomicAdd(&bn[32+c], rs2[0]); }
}

__global__ __launch_bounds__(256) void k_bn_apply(float* __restrict__ h,
    int Tout, const float* __restrict__ bn){
  int idx = blockIdx.x*256 + threadIdx.x;
  int total = NN*32*Tout;
  if(idx >= total) return;
  int c = (idx / Tout) & 31;
  float cnt = (float)(NN*Tout);
  float m = bn[c] / cnt;
  float v = bn[32+c] / cnt - m*m;
  h[idx] = (h[idx] - m) * rsqrtf(v + 1e-5f);
}

// ---------------- prep: skip weight re-layout ----------------
__global__ __launch_bounds__(256) void k_prep(const float* __restrict__ sW,
    const float* __restrict__ sb, float* __restrict__ Bw, float* __restrict__ b2){
  int idx = blockIdx.x*256 + threadIdx.x;
  if(idx >= 65536) return;
  int s = idx & 255; int ic = idx >> 8; int i = ic >> 5; int c = ic & 31;
  Bw[idx] = sW[i*8192 + s*32 + c];
  if(idx < 256){
    float acc = 0.f;
    for(int l = 0; l < 8; l++) acc += sb[l*256 + idx];
    b2[idx] = acc;
  }
}

// ---------------- fold end2@end1 into Wc[12,256], bc[12] ----------------
__global__ __launch_bounds__(256) void k_comb(const float* __restrict__ e1W,
    const float* __restrict__ e1b, const float* __restrict__ e2W,
    const float* __restrict__ e2b, float* __restrict__ Wc, float* __restrict__ bc){
  int idx = blockIdx.x*256 + threadIdx.x;
  if(idx >= 12*256) return;
  int k = idx >> 8, c = idx & 255;
  float acc = 0.f;
  for(int o = 0; o < 512; o++) acc += e2W[k*512+o]*e1W[o*256+c];
  Wc[idx] = acc;
  if(c == 0){
    float b = e2b[k];
    for(int o = 0; o < 512; o++) b += e2W[k*512+o]*e1b[o];
    bc[k] = b;
  }
}

// ---------------- final ----------------
__global__ __launch_bounds__(256) void k_final(const float* __restrict__ skip,
    const float* __restrict__ Wc, const float* __restrict__ bc,
    const float* __restrict__ stdev, const float* __restrict__ means,
    float* __restrict__ out){
  __shared__ float w[3072];
  __shared__ float bcs[12];
  int tid = threadIdx.x;
  for(int j = tid; j < 3072; j += 256){
    int c = j / 12, k = j - c*12;
    w[c*12 + k] = Wc[k*256 + c];
  }
  if(tid < 12) bcs[tid] = bc[tid];
  __syncthreads();
  int idx = blockIdx.x*256 + tid;
  if(idx >= NN*12) return;
  int n = idx / 12, k = idx - n*12;
  const float* sr = skip + (size_t)n*256;
  float acc = bcs[k];
#pragma unroll 8
  for(int c = 0; c < 256; c++) acc += w[c*12 + k]*fmaxf(sr[c], 0.f);
  out[idx] = acc*stdev[n] + means[n];
}

extern "C" void kernel_launch(void* const* d_in, const int* in_sizes, int n_in,
                              void* d_out, int out_size, void* d_ws, size_t ws_size,
                              hipStream_t stream) {
  const float* x      = (const float*)d_in[0];
  const int*   ei     = (const int*)  d_in[1];
  const float* ea     = (const float*)d_in[2];
  const float* startW = (const float*)d_in[3];
  const float* startb = (const float*)d_in[4];
  const float* fW     = (const float*)d_in[5];
  const float* fb     = (const float*)d_in[6];
  const float* gW     = (const float*)d_in[7];
  const float* gb     = (const float*)d_in[8];
  const float* sW     = (const float*)d_in[9];
  const float* sb     = (const float*)d_in[10];
  const float* g0W0   = (const float*)d_in[11];
  const float* g0W1   = (const float*)d_in[12];
  const float* g0b    = (const float*)d_in[13];
  const float* g1W0   = (const float*)d_in[14];
  const float* g1W1   = (const float*)d_in[15];
  const float* g1b    = (const float*)d_in[16];
  const float* e1W    = (const float*)d_in[17];
  const float* e1b    = (const float*)d_in[18];
  const float* e2W    = (const float*)d_in[19];
  const float* e2b    = (const float*)d_in[20];
  float* out = (float*)d_out;
  float* ws  = (float*)d_ws;

  size_t o = 0;
  float* hA    = ws + o; o += (size_t)NN*32*TT;
  float* hB    = ws + o; o += (size_t)NN*32*TT;
  float* glall = ws + o; o += (size_t)NN*256;
  float* stdev = ws + o; o += NN;
  float* means = ws + o; o += NN;
  float* deg   = ws + o; o += NN;
  float* bn    = ws + o; o += 64;
  float* normb = ws + o; o += NE;
  float* xc    = ws + o; o += (size_t)NN*TT;
  float* Bw    = ws + o; o += 256*256;
  float* bias2 = ws + o; o += 256;
  float* Wc    = ws + o; o += 12*256;
  float* bc    = ws + o; o += 16;
  float* tx1   = ws + o; o += (size_t)NN*384;   // doubles as skip buffer at the end
  int*   rowArr = (int*)(ws + o); o += NE;
  float* nrmArr = ws + o; o += NE;
  int*   rowptr = (int*)(ws + o); o += NN+1;
  int*   cnt    = (int*)(ws + o); o += NN;
  int*   woff   = (int*)(ws + o); o += NN;

  hipMemsetAsync(deg, 0, NN*sizeof(float), stream);
  hipMemsetAsync(cnt, 0, NN*sizeof(int), stream);
  k_instnorm<<<(NN+255)/256, 256, 0, stream>>>(x, xc, stdev, means);
  k_start<<<((NN*32*TT)+255)/256, 256, 0, stream>>>(xc, startW, startb, hA);
  k_deg<<<(NE+255)/256, 256, 0, stream>>>(ei, ea, deg);
  k_dinv<<<(NN+255)/256, 256, 0, stream>>>(deg);
  k_norm<<<(NE+255)/256, 256, 0, stream>>>(ei, ea, deg, normb);
  // CSR build (by destination col)
  k_count<<<(NE+255)/256, 256, 0, stream>>>(normb, ei, cnt);
  k_scan<<<1, 1024, 0, stream>>>(cnt, rowptr);
  hipMemcpyAsync(woff, rowptr, NN*sizeof(int), hipMemcpyDeviceToDevice, stream);
  k_place<<<(NE+255)/256, 256, 0, stream>>>(normb, ei, woff, rowArr, nrmArr);
  k_prep<<<256, 256, 0, stream>>>(sW, sb, Bw, bias2);
  k_comb<<<12, 256, 0, stream>>>(e1W, e1b, e2W, e2b, Wc, bc);

  float* cur = hA; float* alt = hB;
  int T = TT;
  const int dil[8] = {1,2,1,2,1,2,1,2};
  for(int i = 0; i < 8; i++){
    int d = dil[i];
    if(i == 1 || i == 5){
      int F = 32*T;
      const float* W0 = (i==1) ? g0W0 : g1W0;
      const float* W1 = (i==1) ? g0W1 : g1W1;
      const float* bb = (i==1) ? g0b  : g1b;
      k_gather<<<NN, F, 0, stream>>>(cur, rowArr, nrmArr, rowptr, tx1, F);
      dim3 gg((NN+63)/64, F/64);
      k_gemm<true><<<gg, 256, 0, stream>>>(cur, W0, tx1, W1, bb, alt, NN, F, F);
      float* tmp = cur; cur = alt; alt = tmp;
    }
    int Tout = T - d;
    hipMemsetAsync(bn, 0, 64*sizeof(float), stream);
    k_gated<<<2048, 256, 0, stream>>>(cur, alt, glall + i*32, fW, fb, gW, gb, i, d, T, Tout);
    dim3 gbn(32, 32);
    k_bn_reduce<<<gbn, 256, 0, stream>>>(alt, Tout, bn);
    k_bn_apply<<<((NN*32*Tout)+255)/256, 256, 0, stream>>>(alt, Tout, bn);
    float* tmp = cur; cur = alt; alt = tmp;
    T = Tout;
  }

  float* skipb = tx1;
  dim3 gs((NN+63)/64, 256/64);
  k_gemm<false><<<gs, 256, 0, stream>>>(glall, Bw, nullptr, nullptr, bias2, skipb, NN, 256, 256);
  k_final<<<((NN*12)+255)/256, 256, 0, stream>>>(skipb, Wc, bc, stdev, means, out);
}

// Round 3
// 688.261 us; speedup vs baseline: 4.4129x; 2.4675x over previous
//
#include <hip/hip_runtime.h>
#include <math.h>

#define NN 20000
#define NE 200000
#define TT 13

typedef short bf16x8 __attribute__((ext_vector_type(8)));
typedef float f32x4 __attribute__((ext_vector_type(4)));

__device__ inline unsigned short f2bf(float f){
  union{float f; unsigned u;} v; v.f = f;
  unsigned r = v.u + 0x7fffu + ((v.u >> 16) & 1u);
  return (unsigned short)(r >> 16);
}
__device__ inline float bf2f(unsigned short h){
  union{unsigned u; float f;} v; v.u = ((unsigned)h) << 16; return v.f;
}

// ---------------- instance norm (over time) + save stdev/means ----------------
__global__ __launch_bounds__(256) void k_instnorm(const float* __restrict__ x,
    float* __restrict__ xc, float* __restrict__ stdev, float* __restrict__ means){
  int n = blockIdx.x*256 + threadIdx.x;
  if(n >= NN) return;
  float v[TT]; float s = 0.f;
#pragma unroll
  for(int t=0;t<TT;t++){ v[t] = x[n*TT+t]; s += v[t]; }
  float m = s * (1.0f/TT);
  float s2 = 0.f;
#pragma unroll
  for(int t=0;t<TT;t++){ v[t] -= m; s2 += v[t]*v[t]; }
  float sd = sqrtf(s2*(1.0f/TT) + 1e-5f);
  float inv = 1.0f/sd;
#pragma unroll
  for(int t=0;t<TT;t++) xc[n*TT+t] = v[t]*inv;
  stdev[n] = sd; means[n] = m;
}

// ---------------- start 1x1 conv ----------------
__global__ __launch_bounds__(256) void k_start(const float* __restrict__ xc,
    const float* __restrict__ sW, const float* __restrict__ sb, float* __restrict__ h){
  int idx = blockIdx.x*256 + threadIdx.x;
  if(idx >= NN*32*TT) return;
  int t = idx % TT; int c = (idx/TT) & 31; int n = idx/(TT*32);
  h[idx] = sW[c]*xc[n*TT+t] + sb[c];
}

// ---------------- GCN edge-norm precompute ----------------
__global__ __launch_bounds__(256) void k_deg(const int* __restrict__ ei,
    const float* __restrict__ ea, float* __restrict__ deg){
  int e = blockIdx.x*256 + threadIdx.x;
  if(e >= NE) return;
  int r = ei[e], c = ei[NE+e];
  float w = (r==c) ? 0.f : ea[e];
  if(w != 0.f) atomicAdd(&deg[r], w);
}

__global__ __launch_bounds__(256) void k_dinv(float* __restrict__ deg){
  int n = blockIdx.x*256 + threadIdx.x;
  if(n >= NN) return;
  float d = deg[n];
  deg[n] = (d > 0.f) ? rsqrtf(d) : 0.f;
}

__global__ __launch_bounds__(256) void k_normcount(const int* __restrict__ ei,
    const float* __restrict__ ea, const float* __restrict__ dinv,
    float* __restrict__ nrm, int* __restrict__ cnt){
  int e = blockIdx.x*256 + threadIdx.x;
  if(e >= NE) return;
  int r = ei[e], c = ei[NE+e];
  float w = (r==c) ? 0.f : ea[e];
  float nv = dinv[r]*w*dinv[c];
  nrm[e] = nv;
  if(nv != 0.f) atomicAdd(&cnt[c], 1);
}

__global__ __launch_bounds__(1024) void k_scan(const int* __restrict__ cnt,
    int* __restrict__ rowptr, int* __restrict__ woff){
  __shared__ int buf[1024];
  __shared__ int carry;
  int tid = threadIdx.x;
  if(tid == 0) carry = 0;
  __syncthreads();
  for(int base = 0; base < NN; base += 1024){
    int i = base + tid;
    int v = (i < NN) ? cnt[i] : 0;
    buf[tid] = v; __syncthreads();
    for(int off = 1; off < 1024; off <<= 1){
      int t = (tid >= off) ? buf[tid-off] : 0;
      __syncthreads();
      buf[tid] += t;
      __syncthreads();
    }
    if(i < NN){ int rp = carry + buf[tid] - v; rowptr[i] = rp; woff[i] = rp; }
    __syncthreads();
    if(tid == 1023) carry += buf[1023];
    __syncthreads();
  }
  if(tid == 0) rowptr[NN] = carry;
}

__global__ __launch_bounds__(256) void k_place(const float* __restrict__ nrm,
    const int* __restrict__ ei, int* __restrict__ woff,
    int* __restrict__ rowArr, float* __restrict__ nrmArr){
  int e = blockIdx.x*256 + threadIdx.x;
  if(e >= NE) return;
  float nv = nrm[e];
  if(nv == 0.f) return;
  int c = ei[NE+e];
  int pos = atomicAdd(&woff[c], 1);
  rowArr[pos] = ei[e];
  nrmArr[pos] = nv;
}

// ---------------- cvt: BN-apply + fp32->bf16 into Acat first half ----------------
__global__ __launch_bounds__(256) void k_cvtbn(const float* __restrict__ h,
    const float* __restrict__ bn, float cntInv, unsigned short* __restrict__ A,
    int T, int half, int Kp){
  int idx = blockIdx.x*256 + threadIdx.x;    // one thread = 2 elements
  if(idx >= NN*half) return;
  int n = idx / half, r = idx - n*half;
  int f0 = 2*r;
  float v0 = h[(size_t)n*2*half + f0];
  float v1 = h[(size_t)n*2*half + f0 + 1];
  int c0 = f0 / T, c1 = (f0+1) / T;
  float m0 = bn[c0]*cntInv, m1 = bn[c1]*cntInv;
  float i0 = rsqrtf(bn[32+c0]*cntInv - m0*m0 + 1e-5f);
  float i1 = rsqrtf(bn[32+c1]*cntInv - m1*m1 + 1e-5f);
  unsigned outw = (unsigned)f2bf((v0-m0)*i0) | ((unsigned)f2bf((v1-m1)*i1) << 16);
  *(unsigned*)(A + (size_t)n*Kp + f0) = outw;
}

// ---------------- gather SpMM (bf16 in/out): Acat[:,F..] = -A^T_norm @ Acat[:,0..F] ----------------
__global__ void k_gather2(const unsigned short* __restrict__ Acat, int Kp, int F,
    const int* __restrict__ rowArr, const float* __restrict__ nrmArr,
    const int* __restrict__ rowptr, unsigned short* __restrict__ dst){
  int node = blockIdx.x;
  int f2 = threadIdx.x;                       // handles features 2*f2, 2*f2+1
  int beg = rowptr[node], end = rowptr[node+1];
  __shared__ int srow[64];
  __shared__ float snrm[64];
  float a0 = 0.f, a1 = 0.f;
  for(int base = beg; base < end; base += 64){
    int m = end - base; if(m > 64) m = 64;
    __syncthreads();
    if(threadIdx.x < m){ srow[threadIdx.x] = rowArr[base+threadIdx.x]; snrm[threadIdx.x] = nrmArr[base+threadIdx.x]; }
    __syncthreads();
    for(int j = 0; j < m; j++){
      unsigned u = *(const unsigned*)(Acat + (size_t)srow[j]*Kp + 2*f2);
      float nv = snrm[j];
      a0 += nv*bf2f((unsigned short)(u & 0xffffu));
      a1 += nv*bf2f((unsigned short)(u >> 16));
    }
  }
  unsigned outw = (unsigned)f2bf(-a0) | ((unsigned)f2bf(-a1) << 16);
  *(unsigned*)(dst + (size_t)node*Kp + F + 2*f2) = outw;
}

// ---------------- prepw: Wt[n][k'] = bf16( k'<F ? W0[k'][n] : W1[k'-F][n] ) ----------------
__global__ __launch_bounds__(256) void k_prepw(const float* __restrict__ W0,
    const float* __restrict__ W1, unsigned short* __restrict__ Wt, int F, int Kp){
  int idx = blockIdx.x*256 + threadIdx.x;
  if(idx >= F*Kp) return;
  int n = idx / Kp, k = idx - n*Kp;
  float v = (k < F) ? W0[k*F + n] : W1[(k-F)*F + n];
  Wt[idx] = f2bf(v);
}

// ---------------- prep skip weights (bf16, [s_out][ic]) + summed bias ----------------
__global__ __launch_bounds__(256) void k_prep2(const float* __restrict__ sW,
    const float* __restrict__ sb, unsigned short* __restrict__ Bwt, float* __restrict__ b2){
  int idx = blockIdx.x*256 + threadIdx.x;
  if(idx >= 65536) return;
  int sOut = idx >> 8; int ic = idx & 255; int i = ic >> 5; int c = ic & 31;
  Bwt[idx] = f2bf(sW[i*8192 + sOut*32 + c]);
  if(idx < 256){
    float acc = 0.f;
    for(int ll = 0; ll < 8; ll++) acc += sb[ll*256 + idx];
    b2[idx] = acc;
  }
}

// ---------------- fold end2@end1 into Wc[12,256], bc[12] ----------------
__global__ __launch_bounds__(256) void k_comb(const float* __restrict__ e1W,
    const float* __restrict__ e1b, const float* __restrict__ e2W,
    const float* __restrict__ e2b, float* __restrict__ Wc, float* __restrict__ bc){
  int idx = blockIdx.x*256 + threadIdx.x;
  if(idx >= 12*256) return;
  int k = idx >> 8, c = idx & 255;
  float acc = 0.f;
  for(int o = 0; o < 512; o++) acc += e2W[k*512+o]*e1W[o*256+c];
  Wc[idx] = acc;
  if(c == 0){
    float b = e2b[k];
    for(int o = 0; o < 512; o++) b += e2W[k*512+o]*e1b[o];
    bc[k] = b;
  }
}

// ---------------- bf16 MFMA GEMM: C = A(bf16,[M][K]) @ Bt(bf16,[N][K])^T + bias ----------------
// 128x64 tile, 256 thr (4 waves), each wave 64x32 via 4x2 of 16x16x32 mfma.
__global__ __launch_bounds__(256) void k_gemm_bf16(const unsigned short* __restrict__ A,
    const unsigned short* __restrict__ Bt, const float* __restrict__ bias,
    float* __restrict__ C, int M, int N, int K){
  __shared__ unsigned short As[128*32];
  __shared__ unsigned short Bs[64*32];
  int tid = threadIdx.x;
  int w = tid >> 6, l = tid & 63, quad = l >> 4, tcol = l & 15;
  int m0 = blockIdx.x*128, n0 = blockIdx.y*64;
  int rw = (w & 1)*64, cw = (w >> 1)*32;
  int sr = tid >> 2, sc = (tid & 3)*8;
  f32x4 acc[4][2];
#pragma unroll
  for(int i=0;i<4;i++)
#pragma unroll
    for(int j=0;j<2;j++) acc[i][j] = (f32x4){0.f,0.f,0.f,0.f};
  for(int k0 = 0; k0 < K; k0 += 32){
    uint4 a0 = *(const uint4*)(A + (size_t)(m0 + sr)*K + k0 + sc);
    uint4 a1 = *(const uint4*)(A + (size_t)(m0 + 64 + sr)*K + k0 + sc);
    uint4 b0 = *(const uint4*)(Bt + (size_t)(n0 + sr)*K + k0 + sc);
    __syncthreads();
    *(uint4*)(As + sr*32 + sc) = a0;
    *(uint4*)(As + (64+sr)*32 + sc) = a1;
    *(uint4*)(Bs + sr*32 + sc) = b0;
    __syncthreads();
    bf16x8 av[4], bv[2];
#pragma unroll
    for(int i=0;i<4;i++) av[i] = *(const bf16x8*)(As + (rw + 16*i + tcol)*32 + quad*8);
#pragma unroll
    for(int j=0;j<2;j++) bv[j] = *(const bf16x8*)(Bs + (cw + 16*j + tcol)*32 + quad*8);
#pragma unroll
    for(int i=0;i<4;i++)
#pragma unroll
      for(int j=0;j<2;j++)
        acc[i][j] = __builtin_amdgcn_mfma_f32_16x16x32_bf16(av[i], bv[j], acc[i][j], 0, 0, 0);
  }
#pragma unroll
  for(int i=0;i<4;i++){
#pragma unroll
    for(int j=0;j<2;j++){
      int col = n0 + cw + 16*j + tcol;
      float bb = bias[col];
#pragma unroll
      for(int r=0;r<4;r++){
        int row = m0 + rw + 16*i + quad*4 + r;
        if(row < M) C[(size_t)row*N + col] = acc[i][j][r] + bb;
      }
    }
  }
}

// ---------------- fused gated conv: per-node MFMA + inline BN-in + stats-out ----------------
// out[c][t] = tanh(f)*sigm(g), f/g = sum_k W0[c][k] h[k][t] + W1[c][k] h[k][t+D]
template<int D,int TIN,int TOUT,bool BNIN,bool STATS,bool WRITEH>
__global__ __launch_bounds__(256) void k_gated2(
    const float* __restrict__ hIn, float* __restrict__ hOut,
    unsigned short* __restrict__ gl,
    const float* __restrict__ bnIn, float* __restrict__ bnOut,
    const float* __restrict__ fWl, const float* __restrict__ fbl,
    const float* __restrict__ gWl, const float* __restrict__ gbl,
    float cntInv){
  constexpr int HW = 32*TIN;
  __shared__ float hs[4][HW];
  __shared__ float bnm[32], bnv[32];
  __shared__ float bnred[64];
  int tid = threadIdx.x;
  int w = tid >> 6, l = tid & 63, quad = l >> 4, tcol = l & 15;
  if(BNIN && tid < 32){
    float ssum = bnIn[tid], s2sum = bnIn[32+tid];
    float m = ssum*cntInv;
    float var = s2sum*cntInv - m*m;
    bnm[tid] = m; bnv[tid] = rsqrtf(var + 1e-5f);
  }
  if(STATS && tid < 64) bnred[tid] = 0.f;
  if(BNIN || STATS) __syncthreads();
  // preload weight A-frags (A[m=c(lane&15)][k=quad*8+j]); khalf0->tap0, khalf1->tap1
  bf16x8 af[2][2], ag[2][2];
  float fbv[8], gbv[8];
#pragma unroll
  for(int i=0;i<2;i++){
    int c = 16*i + tcol;
#pragma unroll
    for(int q=0;q<2;q++){
#pragma unroll
      for(int j=0;j<8;j++){
        int kk = quad*8 + j;
        af[i][q][j] = (short)f2bf(fWl[c*64 + kk*2 + q]);
        ag[i][q][j] = (short)f2bf(gWl[c*64 + kk*2 + q]);
      }
    }
#pragma unroll
    for(int r=0;r<4;r++){
      int cc = 16*i + quad*4 + r;
      fbv[i*4+r] = fbl[cc]; gbv[i*4+r] = gbl[cc];
    }
  }
  float sAcc[8] = {0,0,0,0,0,0,0,0}, s2Acc[8] = {0,0,0,0,0,0,0,0};
  float* hw = hs[w];
  for(int node = blockIdx.x*4 + w; node < NN; node += gridDim.x*4){
    const float* hn = hIn + (size_t)node*HW;
#pragma unroll
    for(int idx = 0; idx < HW; idx += 64){
      int ii = idx + l;
      if(ii < HW){
        float v = hn[ii];
        if(BNIN){ int k = ii / TIN; v = (v - bnm[k])*bnv[k]; }
        hw[ii] = v;
      }
    }
    // B frags: col = t (lane&15), k = quad*8+j; khalf0: h[k][t], khalf1: h[k][t+D]
    bf16x8 b0, b1;
#pragma unroll
    for(int j=0;j<8;j++){
      int kk = quad*8 + j;
      float v0 = 0.f, v1 = 0.f;
      if(tcol < TOUT){
        v0 = hw[kk*TIN + tcol];
        v1 = hw[kk*TIN + tcol + D];
      }
      b0[j] = (short)f2bf(v0);
      b1[j] = (short)f2bf(v1);
    }
    f32x4 accf0 = (f32x4){0.f,0.f,0.f,0.f}, accf1 = accf0, accg0 = accf0, accg1 = accf0;
    accf0 = __builtin_amdgcn_mfma_f32_16x16x32_bf16(af[0][0], b0, accf0, 0,0,0);
    accf0 = __builtin_amdgcn_mfma_f32_16x16x32_bf16(af[0][1], b1, accf0, 0,0,0);
    accf1 = __builtin_amdgcn_mfma_f32_16x16x32_bf16(af[1][0], b0, accf1, 0,0,0);
    accf1 = __builtin_amdgcn_mfma_f32_16x16x32_bf16(af[1][1], b1, accf1, 0,0,0);
    accg0 = __builtin_amdgcn_mfma_f32_16x16x32_bf16(ag[0][0], b0, accg0, 0,0,0);
    accg0 = __builtin_amdgcn_mfma_f32_16x16x32_bf16(ag[0][1], b1, accg0, 0,0,0);
    accg1 = __builtin_amdgcn_mfma_f32_16x16x32_bf16(ag[1][0], b0, accg1, 0,0,0);
    accg1 = __builtin_amdgcn_mfma_f32_16x16x32_bf16(ag[1][1], b1, accg1, 0,0,0);
#pragma unroll
    for(int i=0;i<2;i++){
      f32x4 fa = i ? accf1 : accf0;
      f32x4 ga = i ? accg1 : accg0;
#pragma unroll
      for(int r=0;r<4;r++){
        int c = 16*i + quad*4 + r;
        float f = fa[r] + fbv[i*4+r];
        float g = ga[r] + gbv[i*4+r];
        float gated = tanhf(f) * (1.0f/(1.0f + __expf(-g)));
        if(tcol == TOUT-1) gl[(size_t)node*256 + c] = f2bf(gated);
        if(tcol < TOUT){
          float outv = gated + hw[c*TIN + tcol + D];
          if(WRITEH) hOut[(size_t)node*32*TOUT + c*TOUT + tcol] = outv;
          if(STATS){ sAcc[i*4+r] += outv; s2Acc[i*4+r] += outv*outv; }
        }
      }
    }
  }
  if(STATS){
#pragma unroll
    for(int j=0;j<8;j++){
#pragma unroll
      for(int off=1; off<16; off<<=1){
        sAcc[j]  += __shfl_xor(sAcc[j],  off);
        s2Acc[j] += __shfl_xor(s2Acc[j], off);
      }
    }
    if(tcol == 0){
#pragma unroll
      for(int j=0;j<8;j++){
        int c = 16*(j>>2) + quad*4 + (j&3);
        atomicAdd(&bnred[c], sAcc[j]);
        atomicAdd(&bnred[32+c], s2Acc[j]);
      }
    }
    __syncthreads();
    if(tid < 64) atomicAdd(&bnOut[tid], bnred[tid]);
  }
}

// ---------------- final: out[n,k] = (Wc@relu(skip[n,:]) + bc)*stdev[n]+means[n] ----------------
__global__ __launch_bounds__(256) void k_final(const float* __restrict__ skip,
    const float* __restrict__ Wc, const float* __restrict__ bc,
    const float* __restrict__ stdev, const float* __restrict__ means,
    float* __restrict__ out){
  __shared__ float wsm[3072];
  __shared__ float bcs[12];
  int tid = threadIdx.x;
  for(int j = tid; j < 3072; j += 256){
    int c = j / 12, k = j - c*12;
    wsm[c*12 + k] = Wc[k*256 + c];
  }
  if(tid < 12) bcs[tid] = bc[tid];
  __syncthreads();
  int idx = blockIdx.x*256 + tid;
  if(idx >= NN*12) return;
  int n = idx / 12, k = idx - n*12;
  const float* sr = skip + (size_t)n*256;
  float acc = bcs[k];
#pragma unroll 8
  for(int c = 0; c < 256; c++) acc += wsm[c*12 + k]*fmaxf(sr[c], 0.f);
  out[idx] = acc*stdev[n] + means[n];
}

extern "C" void kernel_launch(void* const* d_in, const int* in_sizes, int n_in,
                              void* d_out, int out_size, void* d_ws, size_t ws_size,
                              hipStream_t stream) {
  const float* x      = (const float*)d_in[0];
  const int*   ei     = (const int*)  d_in[1];
  const float* ea     = (const float*)d_in[2];
  const float* startW = (const float*)d_in[3];
  const float* startb = (const float*)d_in[4];
  const float* fW     = (const float*)d_in[5];
  const float* fb     = (const float*)d_in[6];
  const float* gW     = (const float*)d_in[7];
  const float* gb     = (const float*)d_in[8];
  const float* sW     = (const float*)d_in[9];
  const float* sb     = (const float*)d_in[10];
  const float* g0W0   = (const float*)d_in[11];
  const float* g0W1   = (const float*)d_in[12];
  const float* g0b    = (const float*)d_in[13];
  const float* g1W0   = (const float*)d_in[14];
  const float* g1W1   = (const float*)d_in[15];
  const float* g1b    = (const float*)d_in[16];
  const float* e1W    = (const float*)d_in[17];
  const float* e1b    = (const float*)d_in[18];
  const float* e2W    = (const float*)d_in[19];
  const float* e2b    = (const float*)d_in[20];
  float* out = (float*)d_out;
  float* ws  = (float*)d_ws;

  const int MP = 20096;   // M padded to 128 multiple for GEMM staging reads
  size_t o = 0;
  float* hA    = ws + o; o += (size_t)NN*32*TT;       // 8.32M
  float* hB    = ws + o; o += (size_t)NN*32*TT;       // 8.32M
  unsigned short* Acat = (unsigned short*)(ws + o); o += (size_t)MP*768/2;   // bf16 [MP][768]
  unsigned short* glcat = (unsigned short*)(ws + o); o += (size_t)MP*256/2;  // bf16 [MP][256]
  unsigned short* Wt0  = (unsigned short*)(ws + o); o += 384*768/2;
  unsigned short* Wt1  = (unsigned short*)(ws + o); o += 192*384/2;
  unsigned short* Bwt  = (unsigned short*)(ws + o); o += 256*256/2;
  float* bias2 = ws + o; o += 256;
  float* Wc    = ws + o; o += 12*256;
  float* bc    = ws + o; o += 16;
  float* stdev = ws + o; o += NN;
  float* means = ws + o; o += NN;
  float* xc    = ws + o; o += (size_t)NN*TT + 4;
  float* deg   = ws + o; o += NN;          // deg, cnt, bnstats contiguous -> one memset
  int*   cnt   = (int*)(ws + o); o += NN;
  float* bnstats = ws + o; o += 512;       // 8 layers x (sum[32], sumsq[32])
  float* normb = ws + o; o += NE;
  int*   rowArr = (int*)(ws + o); o += NE;
  float* nrmArr = ws + o; o += NE;
  int*   rowptr = (int*)(ws + o); o += NN + 4;
  int*   woff   = (int*)(ws + o); o += NN;
  float* skipb  = hA;                      // overlay: hA dead by skip-GEMM time

  hipMemsetAsync(deg, 0, (2*NN + 512)*sizeof(float), stream);
  k_instnorm<<<(NN+255)/256, 256, 0, stream>>>(x, xc, stdev, means);
  k_start<<<((NN*32*TT)+255)/256, 256, 0, stream>>>(xc, startW, startb, hA);
  k_deg<<<(NE+255)/256, 256, 0, stream>>>(ei, ea, deg);
  k_dinv<<<(NN+255)/256, 256, 0, stream>>>(deg);
  k_normcount<<<(NE+255)/256, 256, 0, stream>>>(ei, ea, deg, normb, cnt);
  k_scan<<<1, 1024, 0, stream>>>(cnt, rowptr, woff);
  k_place<<<(NE+255)/256, 256, 0, stream>>>(normb, ei, woff, rowArr, nrmArr);
  k_prep2<<<256, 256, 0, stream>>>(sW, sb, Bwt, bias2);
  k_comb<<<12, 256, 0, stream>>>(e1W, e1b, e2W, e2b, Wc, bc);
  k_prepw<<<(384*768+255)/256, 256, 0, stream>>>(g0W0, g0W1, Wt0, 384, 768);
  k_prepw<<<(192*384+255)/256, 256, 0, stream>>>(g1W0, g1W1, Wt1, 192, 384);

  const float* fp = fW; const float* fbp = fb;
  const float* gp = gW; const float* gbp = gb;

  // L0: hA -> hB
  k_gated2<1,13,12,false,true,true><<<512,256,0,stream>>>(hA, hB, glcat+0,
      bnstats, bnstats+0, fp+0*2048, fbp+0*32, gp+0*2048, gbp+0*32, 0.f);
  // GCN0 on BN(hB, stats0): cheb -> hA
  k_cvtbn<<<((NN*192)+255)/256, 256, 0, stream>>>(hB, bnstats+0, 1.f/(NN*12.f), Acat, 12, 192, 768);
  k_gather2<<<NN, 192, 0, stream>>>(Acat, 768, 384, rowArr, nrmArr, rowptr, Acat);
  { dim3 g((MP)/128, 384/64);
    k_gemm_bf16<<<g, 256, 0, stream>>>(Acat, Wt0, g0b, hA, NN, 384, 768); }
  // L1: hA -> hB
  k_gated2<2,12,10,false,true,true><<<512,256,0,stream>>>(hA, hB, glcat+32,
      bnstats, bnstats+64, fp+1*2048, fbp+1*32, gp+1*2048, gbp+1*32, 0.f);
  // L2: hB -> hA
  k_gated2<1,10,9,true,true,true><<<512,256,0,stream>>>(hB, hA, glcat+64,
      bnstats+64, bnstats+128, fp+2*2048, fbp+2*32, gp+2*2048, gbp+2*32, 1.f/(NN*10.f));
  // L3: hA -> hB
  k_gated2<2,9,7,true,true,true><<<512,256,0,stream>>>(hA, hB, glcat+96,
      bnstats+128, bnstats+192, fp+3*2048, fbp+3*32, gp+3*2048, gbp+3*32, 1.f/(NN*9.f));
  // L4: hB -> hA
  k_gated2<1,7,6,true,true,true><<<512,256,0,stream>>>(hB, hA, glcat+128,
      bnstats+192, bnstats+256, fp+4*2048, fbp+4*32, gp+4*2048, gbp+4*32, 1.f/(NN*7.f));
  // GCN1 on BN(hA, stats4): cheb -> hB
  k_cvtbn<<<((NN*96)+255)/256, 256, 0, stream>>>(hA, bnstats+256, 1.f/(NN*6.f), Acat, 6, 96, 384);
  k_gather2<<<NN, 96, 0, stream>>>(Acat, 384, 192, rowArr, nrmArr, rowptr, Acat);
  { dim3 g((MP)/128, 192/64);
    k_gemm_bf16<<<g, 256, 0, stream>>>(Acat, Wt1, g1b, hB, NN, 192, 384); }
  // L5: hB -> hA
  k_gated2<2,6,4,false,true,true><<<512,256,0,stream>>>(hB, hA, glcat+160,
      bnstats, bnstats+320, fp+5*2048, fbp+5*32, gp+5*2048, gbp+5*32, 0.f);
  // L6: hA -> hB
  k_gated2<1,4,3,true,true,true><<<512,256,0,stream>>>(hA, hB, glcat+192,
      bnstats+320, bnstats+384, fp+6*2048, fbp+6*32, gp+6*2048, gbp+6*32, 1.f/(NN*4.f));
  // L7: hB -> (none); only gl
  k_gated2<2,3,1,true,false,false><<<512,256,0,stream>>>(hB, nullptr, glcat+224,
      bnstats+384, bnstats+448, fp+7*2048, fbp+7*32, gp+7*2048, gbp+7*32, 1.f/(NN*3.f));

  // skip GEMM: skipb[N,256] = glcat @ Bwt^T + bias2
  { dim3 g((MP)/128, 256/64);
    k_gemm_bf16<<<g, 256, 0, stream>>>(glcat, Bwt, bias2, skipb, NN, 256, 256); }
  k_final<<<((NN*12)+255)/256, 256, 0, stream>>>(skipb, Wc, bc, stdev, means, out);
}

// Round 4
// 668.653 us; speedup vs baseline: 4.5423x; 1.0293x over previous
//
#include <hip/hip_runtime.h>
#include <math.h>

#define NN 20000
#define NE 200000
#define TT 13

typedef short bf16x8 __attribute__((ext_vector_type(8)));
typedef float f32x4 __attribute__((ext_vector_type(4)));

__device__ inline unsigned short f2bf(float f){
  union{float f; unsigned u;} v; v.f = f;
  unsigned r = v.u + 0x7fffu + ((v.u >> 16) & 1u);
  return (unsigned short)(r >> 16);
}
__device__ inline float bf2f(unsigned short h){
  union{unsigned u; float f;} v; v.u = ((unsigned)h) << 16; return v.f;
}
__device__ inline float fsig(float x){ return __builtin_amdgcn_rcpf(1.f + __expf(-x)); }
__device__ inline float ftanh(float x){ return 2.f*__builtin_amdgcn_rcpf(1.f + __expf(-2.f*x)) - 1.f; }

// ---------------- instance norm (over time) ----------------
__global__ __launch_bounds__(256) void k_instnorm(const float* __restrict__ x,
    float* __restrict__ xc, float* __restrict__ stdev, float* __restrict__ means){
  int n = blockIdx.x*256 + threadIdx.x;
  if(n >= NN) return;
  float v[TT]; float s = 0.f;
#pragma unroll
  for(int t=0;t<TT;t++){ v[t] = x[n*TT+t]; s += v[t]; }
  float m = s * (1.0f/TT);
  float s2 = 0.f;
#pragma unroll
  for(int t=0;t<TT;t++){ v[t] -= m; s2 += v[t]*v[t]; }
  float sd = sqrtf(s2*(1.0f/TT) + 1e-5f);
  float inv = 1.0f/sd;
#pragma unroll
  for(int t=0;t<TT;t++) xc[n*TT+t] = v[t]*inv;
  stdev[n] = sd; means[n] = m;
}

// ---------------- start conv -> bf16 h[n][t][c] ----------------
__global__ __launch_bounds__(256) void k_start2(const float* __restrict__ xc,
    const float* __restrict__ sW, const float* __restrict__ sb, unsigned short* __restrict__ h){
  int idx = blockIdx.x*256 + threadIdx.x;   // one thread = channel pair
  if(idx >= NN*TT*16) return;
  int cp = idx & 15; int t = (idx >> 4) % TT; int n = idx/(16*TT);
  float xv = xc[n*TT+t];
  int c0 = cp*2;
  unsigned u = (unsigned)f2bf(sW[c0]*xv + sb[c0]) | ((unsigned)f2bf(sW[c0+1]*xv + sb[c0+1]) << 16);
  *(unsigned*)(h + (size_t)n*TT*32 + t*32 + c0) = u;
}

// ---------------- GCN edge-norm precompute ----------------
__global__ __launch_bounds__(256) void k_deg(const int* __restrict__ ei,
    const float* __restrict__ ea, float* __restrict__ deg){
  int e = blockIdx.x*256 + threadIdx.x;
  if(e >= NE) return;
  int r = ei[e], c = ei[NE+e];
  float w = (r==c) ? 0.f : ea[e];
  if(w != 0.f) atomicAdd(&deg[r], w);
}

__global__ __launch_bounds__(256) void k_dinv(float* __restrict__ deg){
  int n = blockIdx.x*256 + threadIdx.x;
  if(n >= NN) return;
  float d = deg[n];
  deg[n] = (d > 0.f) ? rsqrtf(d) : 0.f;
}

__global__ __launch_bounds__(256) void k_normcount(const int* __restrict__ ei,
    const float* __restrict__ ea, const float* __restrict__ dinv,
    float* __restrict__ nrm, int* __restrict__ cnt){
  int e = blockIdx.x*256 + threadIdx.x;
  if(e >= NE) return;
  int r = ei[e], c = ei[NE+e];
  float w = (r==c) ? 0.f : ea[e];
  float nv = dinv[r]*w*dinv[c];
  nrm[e] = nv;
  if(nv != 0.f) atomicAdd(&cnt[c], 1);
}

__global__ __launch_bounds__(1024) void k_scan(const int* __restrict__ cnt,
    int* __restrict__ rowptr, int* __restrict__ woff){
  __shared__ int buf[1024];
  __shared__ int carry;
  int tid = threadIdx.x;
  if(tid == 0) carry = 0;
  __syncthreads();
  for(int base = 0; base < NN; base += 1024){
    int i = base + tid;
    int v = (i < NN) ? cnt[i] : 0;
    buf[tid] = v; __syncthreads();
    for(int off = 1; off < 1024; off <<= 1){
      int t = (tid >= off) ? buf[tid-off] : 0;
      __syncthreads();
      buf[tid] += t;
      __syncthreads();
    }
    if(i < NN){ int rp = carry + buf[tid] - v; rowptr[i] = rp; woff[i] = rp; }
    __syncthreads();
    if(tid == 1023) carry += buf[1023];
    __syncthreads();
  }
  if(tid == 0) rowptr[NN] = carry;
}

__global__ __launch_bounds__(256) void k_place(const float* __restrict__ nrm,
    const int* __restrict__ ei, int* __restrict__ woff,
    int* __restrict__ rowArr, float* __restrict__ nrmArr){
  int e = blockIdx.x*256 + threadIdx.x;
  if(e >= NE) return;
  float nv = nrm[e];
  if(nv == 0.f) return;
  int c = ei[NE+e];
  int pos = atomicAdd(&woff[c], 1);
  rowArr[pos] = ei[e];
  nrmArr[pos] = nv;
}

// ---------------- BN-apply (bf16->bf16) into Acat first half; layout [t*32+c] ----------------
__global__ __launch_bounds__(256) void k_cvtbn2(const unsigned short* __restrict__ h,
    const float* __restrict__ bn, float cntInv, unsigned short* __restrict__ A,
    int F, int Kp){
  int idx = blockIdx.x*256 + threadIdx.x;      // one thread = 2 elems
  int half = F >> 1;
  if(idx >= NN*half) return;
  int n = idx / half, r = idx - n*half;
  int k0 = 2*r; int c0 = k0 & 31;
  unsigned u = *(const unsigned*)(h + (size_t)n*F + k0);
  float m0 = bn[c0]*cntInv, m1 = bn[c0+1]*cntInv;
  float i0 = rsqrtf(bn[32+c0]*cntInv - m0*m0 + 1e-5f);
  float i1 = rsqrtf(bn[32+c0+1]*cntInv - m1*m1 + 1e-5f);
  float v0 = (bf2f((unsigned short)(u & 0xffffu)) - m0)*i0;
  float v1 = (bf2f((unsigned short)(u >> 16)) - m1)*i1;
  unsigned outw = (unsigned)f2bf(v0) | ((unsigned)f2bf(v1) << 16);
  *(unsigned*)(A + (size_t)n*Kp + k0) = outw;
}

// ---------------- gather SpMM (bf16): Acat[:,F..] = -sum norm * Acat[row,0..F] ----------------
__global__ void k_gather2(const unsigned short* __restrict__ Acat, int Kp, int F, int F2,
    const int* __restrict__ rowArr, const float* __restrict__ nrmArr,
    const int* __restrict__ rowptr, unsigned short* __restrict__ dst){
  int node = blockIdx.x;
  int f2 = threadIdx.x;
  int beg = rowptr[node], end = rowptr[node+1];
  __shared__ int srow[64];
  __shared__ float snrm[64];
  float a0 = 0.f, a1 = 0.f;
  for(int base = beg; base < end; base += 64){
    int m = end - base; if(m > 64) m = 64;
    __syncthreads();
    if(threadIdx.x < m){ srow[threadIdx.x] = rowArr[base+threadIdx.x]; snrm[threadIdx.x] = nrmArr[base+threadIdx.x]; }
    __syncthreads();
    if(f2 < F2){
      for(int j = 0; j < m; j++){
        unsigned u = *(const unsigned*)(Acat + (size_t)srow[j]*Kp + 2*f2);
        float nv = snrm[j];
        a0 += nv*bf2f((unsigned short)(u & 0xffffu));
        a1 += nv*bf2f((unsigned short)(u >> 16));
      }
    }
  }
  if(f2 < F2){
    unsigned outw = (unsigned)f2bf(-a0) | ((unsigned)f2bf(-a1) << 16);
    *(unsigned*)(dst + (size_t)node*Kp + F + 2*f2) = outw;
  }
}

// ---------------- prepw: permuted GCN weights for [t*32+c] feature order + permuted bias ----------------
__global__ __launch_bounds__(256) void k_prepw2(const float* __restrict__ W0,
    const float* __restrict__ W1, const float* __restrict__ b,
    unsigned short* __restrict__ Wt, float* __restrict__ bPerm, int F, int Kp, int T){
  int idx = blockIdx.x*256 + threadIdx.x;
  if(idx >= F*Kp) return;
  int o = idx / Kp, k = idx - o*Kp;
  int to = o >> 5, co = o & 31; int fout = co*T + to;
  int ki = (k < F) ? k : k - F;
  int ti = ki >> 5, ci = ki & 31; int fin = ci*T + ti;
  float v = (k < F) ? W0[fin*F + fout] : W1[fin*F + fout];
  Wt[idx] = f2bf(v);
  if(k == 0) bPerm[o] = b[fout];
}

// ---------------- prep skip weights bf16 [s_out][ic] + summed bias ----------------
__global__ __launch_bounds__(256) void k_prep2(const float* __restrict__ sW,
    const float* __restrict__ sb, unsigned short* __restrict__ Bwt, float* __restrict__ b2){
  int idx = blockIdx.x*256 + threadIdx.x;
  if(idx >= 65536) return;
  int sOut = idx >> 8; int ic = idx & 255; int i = ic >> 5; int c = ic & 31;
  Bwt[idx] = f2bf(sW[i*8192 + sOut*32 + c]);
  if(idx < 256){
    float acc = 0.f;
    for(int ll = 0; ll < 8; ll++) acc += sb[ll*256 + idx];
    b2[idx] = acc;
  }
}

// ---------------- fold end2@end1 ----------------
__global__ __launch_bounds__(256) void k_comb(const float* __restrict__ e1W,
    const float* __restrict__ e1b, const float* __restrict__ e2W,
    const float* __restrict__ e2b, float* __restrict__ Wc, float* __restrict__ bc){
  int idx = blockIdx.x*256 + threadIdx.x;
  if(idx >= 12*256) return;
  int k = idx >> 8, c = idx & 255;
  float acc = 0.f;
  for(int o = 0; o < 512; o++) acc += e2W[k*512+o]*e1W[o*256+c];
  Wc[idx] = acc;
  if(c == 0){
    float b = e2b[k];
    for(int o = 0; o < 512; o++) b += e2W[k*512+o]*e1b[o];
    bc[k] = b;
  }
}

// ---------------- bf16 MFMA GEMM: C = A[M][K] @ Bt[N][K]^T + bias ----------------
template<bool BOUT>
__global__ __launch_bounds__(256) void k_gemm_bf16(const unsigned short* __restrict__ A,
    const unsigned short* __restrict__ Bt, const float* __restrict__ bias,
    void* __restrict__ Cv, int M, int N, int K){
  __shared__ unsigned short As[128*32];
  __shared__ unsigned short Bs[64*32];
  int tid = threadIdx.x;
  int w = tid >> 6, l = tid & 63, quad = l >> 4, tcol = l & 15;
  int m0 = blockIdx.x*128, n0 = blockIdx.y*64;
  int rw = (w & 1)*64, cw = (w >> 1)*32;
  int sr = tid >> 2, sc = (tid & 3)*8;
  f32x4 acc[4][2];
#pragma unroll
  for(int i=0;i<4;i++)
#pragma unroll
    for(int j=0;j<2;j++) acc[i][j] = (f32x4){0.f,0.f,0.f,0.f};
  for(int k0 = 0; k0 < K; k0 += 32){
    uint4 a0 = *(const uint4*)(A + (size_t)(m0 + sr)*K + k0 + sc);
    uint4 a1 = *(const uint4*)(A + (size_t)(m0 + 64 + sr)*K + k0 + sc);
    uint4 b0 = *(const uint4*)(Bt + (size_t)(n0 + sr)*K + k0 + sc);
    __syncthreads();
    *(uint4*)(As + sr*32 + sc) = a0;
    *(uint4*)(As + (64+sr)*32 + sc) = a1;
    *(uint4*)(Bs + sr*32 + sc) = b0;
    __syncthreads();
    bf16x8 av[4], bv[2];
#pragma unroll
    for(int i=0;i<4;i++) av[i] = *(const bf16x8*)(As + (rw + 16*i + tcol)*32 + quad*8);
#pragma unroll
    for(int j=0;j<2;j++) bv[j] = *(const bf16x8*)(Bs + (cw + 16*j + tcol)*32 + quad*8);
#pragma unroll
    for(int i=0;i<4;i++)
#pragma unroll
      for(int j=0;j<2;j++)
        acc[i][j] = __builtin_amdgcn_mfma_f32_16x16x32_bf16(av[i], bv[j], acc[i][j], 0, 0, 0);
  }
#pragma unroll
  for(int i=0;i<4;i++){
#pragma unroll
    for(int j=0;j<2;j++){
      int col = n0 + cw + 16*j + tcol;
      float bb = bias[col];
#pragma unroll
      for(int r=0;r<4;r++){
        int row = m0 + rw + 16*i + quad*4 + r;
        if(row < M){
          float o = acc[i][j][r] + bb;
          if(BOUT) ((unsigned short*)Cv)[(size_t)row*N + col] = f2bf(o);
          else ((float*)Cv)[(size_t)row*N + col] = o;
        }
      }
    }
  }
}

// ---------------- fused gated conv on bf16 [n][t][c]; wave = node ----------------
template<int D,int TIN,int TOUT,bool BNIN,bool STATS,bool WRITEH>
__global__ __launch_bounds__(256) void k_gated3(
    const unsigned short* __restrict__ hIn, unsigned short* __restrict__ hOut,
    unsigned short* __restrict__ gl,
    const float* __restrict__ bnIn, float* __restrict__ bnOut,
    const float* __restrict__ fWl, const float* __restrict__ fbl,
    const float* __restrict__ gWl, const float* __restrict__ gbl,
    float cntInv){
  constexpr int RS = 40;                      // LDS row stride (ushorts): 16B-aligned, conflict-light
  __shared__ unsigned short hs[4][TIN*RS];
  __shared__ unsigned short ho[4][WRITEH ? TOUT*RS : RS];
  __shared__ float bnm[32], bnv[32];
  __shared__ float bnred[64];
  int tid = threadIdx.x;
  int w = tid >> 6, l = tid & 63, quad = l >> 4, tcol = l & 15;
  if(BNIN && tid < 32){
    float m = bnIn[tid]*cntInv;
    float var = bnIn[32+tid]*cntInv - m*m;
    bnm[tid] = m; bnv[tid] = rsqrtf(var + 1e-5f);
  }
  if(STATS && tid < 64) bnred[tid] = 0.f;
  __syncthreads();
  float sm[8], sv[8];
  if(BNIN){
    int cb = (l & 3)*8;
#pragma unroll
    for(int j=0;j<8;j++){ sm[j] = bnm[cb+j]; sv[j] = bnv[cb+j]; }
  }
  // preload weight B-frags: col=cout(lane&15 + 16i), k=quad*8+j -> (cin, tap)
  bf16x8 bwf[2][2], bwg[2][2];   // [tap][tileI]
  float fbv[2], gbv[2];
#pragma unroll
  for(int i=0;i<2;i++){
    int cout = 16*i + tcol;
#pragma unroll
    for(int q=0;q<2;q++){
#pragma unroll
      for(int j=0;j<8;j++){
        int cin = quad*8 + j;
        bwf[q][i][j] = (short)f2bf(fWl[cout*64 + cin*2 + q]);
        bwg[q][i][j] = (short)f2bf(gWl[cout*64 + cin*2 + q]);
      }
    }
    fbv[i] = fbl[cout]; gbv[i] = gbl[cout];
  }
  int tr = (tcol < TOUT) ? tcol : 0;
  unsigned short* hw = hs[w];
  unsigned short* how = ho[w];
  float sA[2] = {0.f,0.f}, s2A[2] = {0.f,0.f};
  const int stride = gridDim.x*4;
  int node = blockIdx.x*4 + w;
  uint4 v = {0,0,0,0};
  if(node < NN && l < TIN*4) v = *(const uint4*)(hIn + (size_t)node*TIN*32 + l*8);
  for(; node < NN; node += stride){
    // stage current node (BN applied on the fly)
    if(l < TIN*4){
      int ts = l >> 2, cb = (l & 3)*8;
      if(BNIN){
        unsigned short tmp[8];
        const unsigned short* up = (const unsigned short*)&v;
#pragma unroll
        for(int j=0;j<8;j++) tmp[j] = f2bf((bf2f(up[j]) - sm[j])*sv[j]);
        *(uint4*)(hw + ts*RS + cb) = *(const uint4*)tmp;
      } else {
        *(uint4*)(hw + ts*RS + cb) = v;
      }
    }
    // prefetch next node
    int nn2 = node + stride;
    if(nn2 < NN && l < TIN*4) v = *(const uint4*)(hIn + (size_t)nn2*TIN*32 + l*8);
    // A-frags: row=t(tcol), k-chunk0 = h[t][:], chunk1 = h[t+D][:]
    bf16x8 a0 = *(const bf16x8*)(hw + tr*RS + quad*8);
    bf16x8 a1 = *(const bf16x8*)(hw + (tr+D)*RS + quad*8);
    f32x4 accf[2], accg[2];
#pragma unroll
    for(int i=0;i<2;i++){ accf[i] = (f32x4){0.f,0.f,0.f,0.f}; accg[i] = (f32x4){0.f,0.f,0.f,0.f}; }
#pragma unroll
    for(int i=0;i<2;i++){
      accf[i] = __builtin_amdgcn_mfma_f32_16x16x32_bf16(a0, bwf[0][i], accf[i], 0,0,0);
      accf[i] = __builtin_amdgcn_mfma_f32_16x16x32_bf16(a1, bwf[1][i], accf[i], 0,0,0);
      accg[i] = __builtin_amdgcn_mfma_f32_16x16x32_bf16(a0, bwg[0][i], accg[i], 0,0,0);
      accg[i] = __builtin_amdgcn_mfma_f32_16x16x32_bf16(a1, bwg[1][i], accg[i], 0,0,0);
    }
#pragma unroll
    for(int i=0;i<2;i++){
      int cout = 16*i + tcol;
#pragma unroll
      for(int r=0;r<4;r++){
        int t = quad*4 + r;
        if(t < TOUT){
          float f = accf[i][r] + fbv[i];
          float g = accg[i][r] + gbv[i];
          float gated = ftanh(f)*fsig(g);
          if(t == TOUT-1) gl[(size_t)node*256 + cout] = f2bf(gated);
          float outv = gated + bf2f(hw[(t+D)*RS + cout]);
          if(WRITEH) how[t*RS + cout] = f2bf(outv);
          if(STATS){ sA[i] += outv; s2A[i] += outv*outv; }
        }
      }
    }
    if(WRITEH && l < TOUT*4){
      int to = l >> 2, cb = (l & 3)*8;
      *(uint4*)(hOut + (size_t)node*TOUT*32 + to*32 + cb) = *(const uint4*)(how + to*RS + cb);
    }
  }
  if(STATS){
#pragma unroll
    for(int i=0;i<2;i++){
      sA[i]  += __shfl_xor(sA[i], 16);  sA[i]  += __shfl_xor(sA[i], 32);
      s2A[i] += __shfl_xor(s2A[i], 16); s2A[i] += __shfl_xor(s2A[i], 32);
    }
    if(l < 16){
#pragma unroll
      for(int i=0;i<2;i++){
        atomicAdd(&bnred[16*i + l], sA[i]);
        atomicAdd(&bnred[32 + 16*i + l], s2A[i]);
      }
    }
    __syncthreads();
    if(tid < 64) atomicAdd(&bnOut[tid], bnred[tid]);
  }
}

// ---------------- final ----------------
__global__ __launch_bounds__(256) void k_final(const float* __restrict__ skip,
    const float* __restrict__ Wc, const float* __restrict__ bc,
    const float* __restrict__ stdev, const float* __restrict__ means,
    float* __restrict__ out){
  __shared__ float wsm[3072];
  __shared__ float bcs[12];
  int tid = threadIdx.x;
  for(int j = tid; j < 3072; j += 256){
    int c = j / 12, k = j - c*12;
    wsm[c*12 + k] = Wc[k*256 + c];
  }
  if(tid < 12) bcs[tid] = bc[tid];
  __syncthreads();
  int idx = blockIdx.x*256 + tid;
  if(idx >= NN*12) return;
  int n = idx / 12, k = idx - n*12;
  const float* sr = skip + (size_t)n*256;
  float acc = bcs[k];
#pragma unroll 8
  for(int c = 0; c < 256; c++) acc += wsm[c*12 + k]*fmaxf(sr[c], 0.f);
  out[idx] = acc*stdev[n] + means[n];
}

extern "C" void kernel_launch(void* const* d_in, const int* in_sizes, int n_in,
                              void* d_out, int out_size, void* d_ws, size_t ws_size,
                              hipStream_t stream) {
  const float* x      = (const float*)d_in[0];
  const int*   ei     = (const int*)  d_in[1];
  const float* ea     = (const float*)d_in[2];
  const float* startW = (const float*)d_in[3];
  const float* startb = (const float*)d_in[4];
  const float* fW     = (const float*)d_in[5];
  const float* fb     = (const float*)d_in[6];
  const float* gW     = (const float*)d_in[7];
  const float* gb     = (const float*)d_in[8];
  const float* sW     = (const float*)d_in[9];
  const float* sb     = (const float*)d_in[10];
  const float* g0W0   = (const float*)d_in[11];
  const float* g0W1   = (const float*)d_in[12];
  const float* g0b    = (const float*)d_in[13];
  const float* g1W0   = (const float*)d_in[14];
  const float* g1W1   = (const float*)d_in[15];
  const float* g1b    = (const float*)d_in[16];
  const float* e1W    = (const float*)d_in[17];
  const float* e1b    = (const float*)d_in[18];
  const float* e2W    = (const float*)d_in[19];
  const float* e2b    = (const float*)d_in[20];
  float* out = (float*)d_out;
  float* ws  = (float*)d_ws;

  const int MP = 20096;
  size_t o = 0;
  unsigned short* hA = (unsigned short*)(ws + o); o += (size_t)NN*208;   // bf16 [NN][13*32]
  unsigned short* hB = (unsigned short*)(ws + o); o += (size_t)NN*208;
  unsigned short* Acat  = (unsigned short*)(ws + o); o += (size_t)MP*384;  // bf16 [MP][768]
  unsigned short* glcat = (unsigned short*)(ws + o); o += (size_t)MP*128;  // bf16 [MP][256]
  unsigned short* Wt0 = (unsigned short*)(ws + o); o += 147456;
  unsigned short* Wt1 = (unsigned short*)(ws + o); o += 36864;
  unsigned short* Bwt = (unsigned short*)(ws + o); o += 32768;
  float* bP0   = ws + o; o += 384;
  float* bP1   = ws + o; o += 192;
  float* bias2 = ws + o; o += 256;
  float* Wc    = ws + o; o += 3072;
  float* bc    = ws + o; o += 16;
  float* stdev = ws + o; o += NN;
  float* means = ws + o; o += NN;
  float* xc    = ws + o; o += (size_t)NN*TT;
  float* deg   = ws + o; o += NN;            // deg, cnt, bnstats contiguous -> one memset
  int*   cnt   = (int*)(ws + o); o += NN;
  float* bnstats = ws + o; o += 512;
  float* normb = ws + o; o += NE;
  int*   rowArr = (int*)(ws + o); o += NE;
  float* nrmArr = ws + o; o += NE;
  int*   rowptr = (int*)(ws + o); o += NN + 4;
  int*   woff   = (int*)(ws + o); o += NN;
  float* skipb  = (float*)hA;                // overlay: hA+hB dead by skip-GEMM time

  hipMemsetAsync(deg, 0, (2*NN + 512)*sizeof(float), stream);
  k_instnorm<<<(NN+255)/256, 256, 0, stream>>>(x, xc, stdev, means);
  k_start2<<<((NN*TT*16)+255)/256, 256, 0, stream>>>(xc, startW, startb, hA);
  k_deg<<<(NE+255)/256, 256, 0, stream>>>(ei, ea, deg);
  k_dinv<<<(NN+255)/256, 256, 0, stream>>>(deg);
  k_normcount<<<(NE+255)/256, 256, 0, stream>>>(ei, ea, deg, normb, cnt);
  k_scan<<<1, 1024, 0, stream>>>(cnt, rowptr, woff);
  k_place<<<(NE+255)/256, 256, 0, stream>>>(normb, ei, woff, rowArr, nrmArr);
  k_prep2<<<256, 256, 0, stream>>>(sW, sb, Bwt, bias2);
  k_comb<<<12, 256, 0, stream>>>(e1W, e1b, e2W, e2b, Wc, bc);
  k_prepw2<<<(384*768+255)/256, 256, 0, stream>>>(g0W0, g0W1, g0b, Wt0, bP0, 384, 768, 12);
  k_prepw2<<<(192*384+255)/256, 256, 0, stream>>>(g1W0, g1W1, g1b, Wt1, bP1, 192, 384, 6);

  const int GB = 1280;   // gated grid: 5 waves/SIMD
  // L0: hA -> hB
  k_gated3<1,13,12,false,true,true><<<GB,256,0,stream>>>(hA, hB, glcat+0,
      bnstats, bnstats+0, fW+0*2048, fb+0*32, gW+0*2048, gb+0*32, 0.f);
  // GCN0: BN(hB) -> Acat ; gather ; GEMM -> hA (T=12)
  k_cvtbn2<<<((NN*192)+255)/256, 256, 0, stream>>>(hB, bnstats+0, 1.f/(NN*12.f), Acat, 384, 768);
  k_gather2<<<NN, 192, 0, stream>>>(Acat, 768, 384, 192, rowArr, nrmArr, rowptr, Acat);
  { dim3 g(MP/128, 384/64);
    k_gemm_bf16<true><<<g, 256, 0, stream>>>(Acat, Wt0, bP0, hA, NN, 384, 768); }
  // L1: hA -> hB
  k_gated3<2,12,10,false,true,true><<<GB,256,0,stream>>>(hA, hB, glcat+32,
      bnstats, bnstats+64, fW+1*2048, fb+1*32, gW+1*2048, gb+1*32, 0.f);
  // L2: hB -> hA
  k_gated3<1,10,9,true,true,true><<<GB,256,0,stream>>>(hB, hA, glcat+64,
      bnstats+64, bnstats+128, fW+2*2048, fb+2*32, gW+2*2048, gb+2*32, 1.f/(NN*10.f));
  // L3: hA -> hB
  k_gated3<2,9,7,true,true,true><<<GB,256,0,stream>>>(hA, hB, glcat+96,
      bnstats+128, bnstats+192, fW+3*2048, fb+3*32, gW+3*2048, gb+3*32, 1.f/(NN*9.f));
  // L4: hB -> hA
  k_gated3<1,7,6,true,true,true><<<GB,256,0,stream>>>(hB, hA, glcat+128,
      bnstats+192, bnstats+256, fW+4*2048, fb+4*32, gW+4*2048, gb+4*32, 1.f/(NN*7.f));
  // GCN1: BN(hA) -> Acat ; gather ; GEMM -> hB (T=6)
  k_cvtbn2<<<((NN*96)+255)/256, 256, 0, stream>>>(hA, bnstats+256, 1.f/(NN*6.f), Acat, 192, 384);
  k_gather2<<<NN, 128, 0, stream>>>(Acat, 384, 192, 96, rowArr, nrmArr, rowptr, Acat);
  { dim3 g(MP/128, 192/64);
    k_gemm_bf16<true><<<g, 256, 0, stream>>>(Acat, Wt1, bP1, hB, NN, 192, 384); }
  // L5: hB -> hA
  k_gated3<2,6,4,false,true,true><<<GB,256,0,stream>>>(hB, hA, glcat+160,
      bnstats, bnstats+320, fW+5*2048, fb+5*32, gW+5*2048, gb+5*32, 0.f);
  // L6: hA -> hB
  k_gated3<1,4,3,true,true,true><<<GB,256,0,stream>>>(hA, hB, glcat+192,
      bnstats+320, bnstats+384, fW+6*2048, fb+6*32, gW+6*2048, gb+6*32, 1.f/(NN*4.f));
  // L7: hB -> (gl only)
  k_gated3<2,3,1,true,false,false><<<GB,256,0,stream>>>(hB, nullptr, glcat+224,
      bnstats+384, bnstats+448, fW+7*2048, fb+7*32, gW+7*2048, gb+7*32, 1.f/(NN*3.f));

  // skip GEMM (fp32 out): skipb[N,256] = glcat @ Bwt^T + bias2
  { dim3 g(MP/128, 256/64);
    k_gemm_bf16<false><<<g, 256, 0, stream>>>(glcat, Bwt, bias2, skipb, NN, 256, 256); }
  k_final<<<((NN*12)+255)/256, 256, 0, stream>>>(skipb, Wc, bc, stdev, means, out);
}

// Round 5
// 618.423 us; speedup vs baseline: 4.9112x; 1.0812x over previous
//
#include <hip/hip_runtime.h>
#include <math.h>

#define NN 20000
#define NE 200000
#define TT 13

typedef short bf16x8 __attribute__((ext_vector_type(8)));
typedef float f32x4 __attribute__((ext_vector_type(4)));

__device__ inline unsigned short f2bf(float f){
  union{float f; unsigned u;} v; v.f = f;
  unsigned r = v.u + 0x7fffu + ((v.u >> 16) & 1u);
  return (unsigned short)(r >> 16);
}
__device__ inline float bf2f(unsigned short h){
  union{unsigned u; float f;} v; v.u = ((unsigned)h) << 16; return v.f;
}
__device__ inline float fsig(float x){ return __builtin_amdgcn_rcpf(1.f + __expf(-x)); }
__device__ inline float ftanh(float x){ return 2.f*__builtin_amdgcn_rcpf(1.f + __expf(-2.f*x)) - 1.f; }

// ---------------- instance norm (over time) ----------------
__global__ __launch_bounds__(256) void k_instnorm(const float* __restrict__ x,
    float* __restrict__ xc, float* __restrict__ stdev, float* __restrict__ means){
  int n = blockIdx.x*256 + threadIdx.x;
  if(n >= NN) return;
  float v[TT]; float s = 0.f;
#pragma unroll
  for(int t=0;t<TT;t++){ v[t] = x[n*TT+t]; s += v[t]; }
  float m = s * (1.0f/TT);
  float s2 = 0.f;
#pragma unroll
  for(int t=0;t<TT;t++){ v[t] -= m; s2 += v[t]*v[t]; }
  float sd = sqrtf(s2*(1.0f/TT) + 1e-5f);
  float inv = 1.0f/sd;
#pragma unroll
  for(int t=0;t<TT;t++) xc[n*TT+t] = v[t]*inv;
  stdev[n] = sd; means[n] = m;
}

// ---------------- start conv -> bf16 h[n][t][c] ----------------
__global__ __launch_bounds__(256) void k_start2(const float* __restrict__ xc,
    const float* __restrict__ sW, const float* __restrict__ sb, unsigned short* __restrict__ h){
  int idx = blockIdx.x*256 + threadIdx.x;   // one thread = channel pair
  if(idx >= NN*TT*16) return;
  int cp = idx & 15; int t = (idx >> 4) % TT; int n = idx/(16*TT);
  float xv = xc[n*TT+t];
  int c0 = cp*2;
  unsigned u = (unsigned)f2bf(sW[c0]*xv + sb[c0]) | ((unsigned)f2bf(sW[c0+1]*xv + sb[c0+1]) << 16);
  *(unsigned*)(h + (size_t)n*TT*32 + t*32 + c0) = u;
}

// ---------------- GCN edge-norm precompute ----------------
__global__ __launch_bounds__(256) void k_deg(const int* __restrict__ ei,
    const float* __restrict__ ea, float* __restrict__ deg){
  int e = blockIdx.x*256 + threadIdx.x;
  if(e >= NE) return;
  int r = ei[e], c = ei[NE+e];
  float w = (r==c) ? 0.f : ea[e];
  if(w != 0.f) atomicAdd(&deg[r], w);
}

__global__ __launch_bounds__(256) void k_dinv(float* __restrict__ deg){
  int n = blockIdx.x*256 + threadIdx.x;
  if(n >= NN) return;
  float d = deg[n];
  deg[n] = (d > 0.f) ? rsqrtf(d) : 0.f;
}

__global__ __launch_bounds__(256) void k_normcount(const int* __restrict__ ei,
    const float* __restrict__ ea, const float* __restrict__ dinv,
    float* __restrict__ nrm, int* __restrict__ cnt){
  int e = blockIdx.x*256 + threadIdx.x;
  if(e >= NE) return;
  int r = ei[e], c = ei[NE+e];
  float w = (r==c) ? 0.f : ea[e];
  float nv = dinv[r]*w*dinv[c];
  nrm[e] = nv;
  if(nv != 0.f) atomicAdd(&cnt[c], 1);
}

__global__ __launch_bounds__(1024) void k_scan(const int* __restrict__ cnt,
    int* __restrict__ rowptr, int* __restrict__ woff){
  __shared__ int buf[1024];
  __shared__ int carry;
  int tid = threadIdx.x;
  if(tid == 0) carry = 0;
  __syncthreads();
  for(int base = 0; base < NN; base += 1024){
    int i = base + tid;
    int v = (i < NN) ? cnt[i] : 0;
    buf[tid] = v; __syncthreads();
    for(int off = 1; off < 1024; off <<= 1){
      int t = (tid >= off) ? buf[tid-off] : 0;
      __syncthreads();
      buf[tid] += t;
      __syncthreads();
    }
    if(i < NN){ int rp = carry + buf[tid] - v; rowptr[i] = rp; woff[i] = rp; }
    __syncthreads();
    if(tid == 1023) carry += buf[1023];
    __syncthreads();
  }
  if(tid == 0) rowptr[NN] = carry;
}

__global__ __launch_bounds__(256) void k_place(const float* __restrict__ nrm,
    const int* __restrict__ ei, int* __restrict__ woff,
    int* __restrict__ rowArr, float* __restrict__ nrmArr){
  int e = blockIdx.x*256 + threadIdx.x;
  if(e >= NE) return;
  float nv = nrm[e];
  if(nv == 0.f) return;
  int c = ei[NE+e];
  int pos = atomicAdd(&woff[c], 1);
  rowArr[pos] = ei[e];
  nrmArr[pos] = nv;
}

// ---------------- pack gated-conv weights into per-lane MFMA fragments ----------------
// Wfrag: [8 layers][8 chunks][64 lanes][8] bf16 ; chunk = fg*4 + q*2 + i
// Bfrag: [8 layers][64 lanes][4] float = {fb[tcol], fb[16+tcol], gb[tcol], gb[16+tcol]}
__global__ __launch_bounds__(256) void k_prepg(const float* __restrict__ fW,
    const float* __restrict__ fb, const float* __restrict__ gW, const float* __restrict__ gb,
    unsigned short* __restrict__ Wfrag, float* __restrict__ Bfrag){
  int idx = blockIdx.x*256 + threadIdx.x;
  if(idx < 8*8*64*8){
    int j = idx & 7; int lane = (idx >> 3) & 63; int chunk = (idx >> 9) & 7; int layer = idx >> 12;
    int fg = chunk >> 2; int q = (chunk >> 1) & 1; int i = chunk & 1;
    int quad = lane >> 4, tcol = lane & 15;
    int cout = 16*i + tcol, cin = quad*8 + j;
    const float* W = fg ? gW : fW;
    Wfrag[idx] = f2bf(W[layer*2048 + cout*64 + cin*2 + q]);
  }
  if(idx < 8*64*4){
    int r = idx & 3; int lane = (idx >> 2) & 63; int layer = idx >> 8;
    int tcol = lane & 15;
    float v;
    if(r == 0)      v = fb[layer*32 + tcol];
    else if(r == 1) v = fb[layer*32 + 16 + tcol];
    else if(r == 2) v = gb[layer*32 + tcol];
    else            v = gb[layer*32 + 16 + tcol];
    Bfrag[idx] = v;
  }
}

// ---------------- BN-apply (bf16->bf16) into Acat first half ----------------
__global__ __launch_bounds__(256) void k_cvtbn2(const unsigned short* __restrict__ h,
    const float* __restrict__ bn, float cntInv, unsigned short* __restrict__ A,
    int F, int Kp){
  int idx = blockIdx.x*256 + threadIdx.x;      // one thread = 2 elems
  int half = F >> 1;
  if(idx >= NN*half) return;
  int n = idx / half, r = idx - n*half;
  int k0 = 2*r; int c0 = k0 & 31;
  unsigned u = *(const unsigned*)(h + (size_t)n*F + k0);
  float m0 = bn[c0]*cntInv, m1 = bn[c0+1]*cntInv;
  float i0 = rsqrtf(bn[32+c0]*cntInv - m0*m0 + 1e-5f);
  float i1 = rsqrtf(bn[32+c0+1]*cntInv - m1*m1 + 1e-5f);
  float v0 = (bf2f((unsigned short)(u & 0xffffu)) - m0)*i0;
  float v1 = (bf2f((unsigned short)(u >> 16)) - m1)*i1;
  unsigned outw = (unsigned)f2bf(v0) | ((unsigned)f2bf(v1) << 16);
  *(unsigned*)(A + (size_t)n*Kp + k0) = outw;
}

// ---------------- gather SpMM (bf16): Acat[:,F..] = -sum norm * Acat[row,0..F] ----------------
__global__ void k_gather2(const unsigned short* __restrict__ Acat, int Kp, int F, int F2,
    const int* __restrict__ rowArr, const float* __restrict__ nrmArr,
    const int* __restrict__ rowptr, unsigned short* __restrict__ dst){
  int node = blockIdx.x;
  int f2 = threadIdx.x;
  int beg = rowptr[node], end = rowptr[node+1];
  __shared__ int srow[64];
  __shared__ float snrm[64];
  float a0 = 0.f, a1 = 0.f;
  for(int base = beg; base < end; base += 64){
    int m = end - base; if(m > 64) m = 64;
    __syncthreads();
    if(threadIdx.x < m){ srow[threadIdx.x] = rowArr[base+threadIdx.x]; snrm[threadIdx.x] = nrmArr[base+threadIdx.x]; }
    __syncthreads();
    if(f2 < F2){
      for(int j = 0; j < m; j++){
        unsigned u = *(const unsigned*)(Acat + (size_t)srow[j]*Kp + 2*f2);
        float nv = snrm[j];
        a0 += nv*bf2f((unsigned short)(u & 0xffffu));
        a1 += nv*bf2f((unsigned short)(u >> 16));
      }
    }
  }
  if(f2 < F2){
    unsigned outw = (unsigned)f2bf(-a0) | ((unsigned)f2bf(-a1) << 16);
    *(unsigned*)(dst + (size_t)node*Kp + F + 2*f2) = outw;
  }
}

// ---------------- prepw: permuted GCN weights for [t*32+c] feature order ----------------
__global__ __launch_bounds__(256) void k_prepw2(const float* __restrict__ W0,
    const float* __restrict__ W1, const float* __restrict__ b,
    unsigned short* __restrict__ Wt, float* __restrict__ bPerm, int F, int Kp, int T){
  int idx = blockIdx.x*256 + threadIdx.x;
  if(idx >= F*Kp) return;
  int o = idx / Kp, k = idx - o*Kp;
  int to = o >> 5, co = o & 31; int fout = co*T + to;
  int ki = (k < F) ? k : k - F;
  int ti = ki >> 5, ci = ki & 31; int fin = ci*T + ti;
  float v = (k < F) ? W0[fin*F + fout] : W1[fin*F + fout];
  Wt[idx] = f2bf(v);
  if(k == 0) bPerm[o] = b[fout];
}

// ---------------- prep skip weights bf16 [s_out][ic] + summed bias ----------------
__global__ __launch_bounds__(256) void k_prep2(const float* __restrict__ sW,
    const float* __restrict__ sb, unsigned short* __restrict__ Bwt, float* __restrict__ b2){
  int idx = blockIdx.x*256 + threadIdx.x;
  if(idx >= 65536) return;
  int sOut = idx >> 8; int ic = idx & 255; int i = ic >> 5; int c = ic & 31;
  Bwt[idx] = f2bf(sW[i*8192 + sOut*32 + c]);
  if(idx < 256){
    float acc = 0.f;
    for(int ll = 0; ll < 8; ll++) acc += sb[ll*256 + idx];
    b2[idx] = acc;
  }
}

// ---------------- fold end2@end1 ----------------
__global__ __launch_bounds__(256) void k_comb(const float* __restrict__ e1W,
    const float* __restrict__ e1b, const float* __restrict__ e2W,
    const float* __restrict__ e2b, float* __restrict__ Wc, float* __restrict__ bc){
  int idx = blockIdx.x*256 + threadIdx.x;
  if(idx >= 12*256) return;
  int k = idx >> 8, c = idx & 255;
  float acc = 0.f;
  for(int o = 0; o < 512; o++) acc += e2W[k*512+o]*e1W[o*256+c];
  Wc[idx] = acc;
  if(c == 0){
    float b = e2b[k];
    for(int o = 0; o < 512; o++) b += e2W[k*512+o]*e1b[o];
    bc[k] = b;
  }
}

// ---------------- bf16 MFMA GEMM: C = A[M][K] @ Bt[N][K]^T + bias ----------------
template<bool BOUT>
__global__ __launch_bounds__(256) void k_gemm_bf16(const unsigned short* __restrict__ A,
    const unsigned short* __restrict__ Bt, const float* __restrict__ bias,
    void* __restrict__ Cv, int M, int N, int K){
  __shared__ unsigned short As[128*32];
  __shared__ unsigned short Bs[64*32];
  int tid = threadIdx.x;
  int w = tid >> 6, l = tid & 63, quad = l >> 4, tcol = l & 15;
  int m0 = blockIdx.x*128, n0 = blockIdx.y*64;
  int rw = (w & 1)*64, cw = (w >> 1)*32;
  int sr = tid >> 2, sc = (tid & 3)*8;
  f32x4 acc[4][2];
#pragma unroll
  for(int i=0;i<4;i++)
#pragma unroll
    for(int j=0;j<2;j++) acc[i][j] = (f32x4){0.f,0.f,0.f,0.f};
  for(int k0 = 0; k0 < K; k0 += 32){
    uint4 a0 = *(const uint4*)(A + (size_t)(m0 + sr)*K + k0 + sc);
    uint4 a1 = *(const uint4*)(A + (size_t)(m0 + 64 + sr)*K + k0 + sc);
    uint4 b0 = *(const uint4*)(Bt + (size_t)(n0 + sr)*K + k0 + sc);
    __syncthreads();
    *(uint4*)(As + sr*32 + sc) = a0;
    *(uint4*)(As + (64+sr)*32 + sc) = a1;
    *(uint4*)(Bs + sr*32 + sc) = b0;
    __syncthreads();
    bf16x8 av[4], bv[2];
#pragma unroll
    for(int i=0;i<4;i++) av[i] = *(const bf16x8*)(As + (rw + 16*i + tcol)*32 + quad*8);
#pragma unroll
    for(int j=0;j<2;j++) bv[j] = *(const bf16x8*)(Bs + (cw + 16*j + tcol)*32 + quad*8);
#pragma unroll
    for(int i=0;i<4;i++)
#pragma unroll
      for(int j=0;j<2;j++)
        acc[i][j] = __builtin_amdgcn_mfma_f32_16x16x32_bf16(av[i], bv[j], acc[i][j], 0, 0, 0);
  }
#pragma unroll
  for(int i=0;i<4;i++){
#pragma unroll
    for(int j=0;j<2;j++){
      int col = n0 + cw + 16*j + tcol;
      float bb = bias[col];
#pragma unroll
      for(int r=0;r<4;r++){
        int row = m0 + rw + 16*i + quad*4 + r;
        if(row < M){
          float o = acc[i][j][r] + bb;
          if(BOUT) ((unsigned short*)Cv)[(size_t)row*N + col] = f2bf(o);
          else ((float*)Cv)[(size_t)row*N + col] = o;
        }
      }
    }
  }
}

// ---------------- fused gated conv on bf16 [n][t][c]; wave = node ----------------
template<int D,int TIN,int TOUT,bool BNIN,bool STATS,bool WRITEH>
__global__ __launch_bounds__(256) void k_gated4(
    const unsigned short* __restrict__ hIn, unsigned short* __restrict__ hOut,
    unsigned short* __restrict__ gl,
    const float* __restrict__ bnIn, float* __restrict__ bnOut,
    const unsigned short* __restrict__ Wfrag, const float* __restrict__ Bfrag,
    int layer, float cntInv){
  constexpr int RS = 40;                      // LDS row stride (ushorts)
  __shared__ unsigned short hs[4][TIN*RS];
  __shared__ unsigned short ho[4][WRITEH ? TOUT*RS : RS];
  __shared__ float bnm[32], bnv[32];
  __shared__ float bnred[64];
  int tid = threadIdx.x;
  int w = tid >> 6, l = tid & 63, quad = l >> 4, tcol = l & 15;
  if(BNIN && tid < 32){
    float m = bnIn[tid]*cntInv;
    float var = bnIn[32+tid]*cntInv - m*m;
    bnm[tid] = m; bnv[tid] = rsqrtf(var + 1e-5f);
  }
  if(STATS && tid < 64) bnred[tid] = 0.f;
  __syncthreads();
  float sm[8], sv[8];
  if(BNIN){
    int cb = (l & 3)*8;
#pragma unroll
    for(int j=0;j<8;j++){ sm[j] = bnm[cb+j]; sv[j] = bnv[cb+j]; }
  }
  // coalesced fragment preload: 8 x 16B/lane + 1 x 16B/lane
  const unsigned short* wfr = Wfrag + layer*4096;
  bf16x8 bwf[2][2], bwg[2][2];   // [tap q][tile i]
#pragma unroll
  for(int q=0;q<2;q++)
#pragma unroll
    for(int i=0;i<2;i++){
      bwf[q][i] = *(const bf16x8*)(wfr + ((q*2+i)*64 + l)*8);
      bwg[q][i] = *(const bf16x8*)(wfr + ((4 + q*2+i)*64 + l)*8);
    }
  float4 bv4 = *(const float4*)(Bfrag + layer*256 + l*4);
  float fbv[2] = {bv4.x, bv4.y}, gbv[2] = {bv4.z, bv4.w};

  int tr = (tcol < TOUT) ? tcol : 0;
  unsigned short* hw = hs[w];
  unsigned short* how = ho[w];
  float sA[2] = {0.f,0.f}, s2A[2] = {0.f,0.f};
  const int stride = gridDim.x*4;
  int node = blockIdx.x*4 + w;
  uint4 v = {0,0,0,0};
  if(node < NN && l < TIN*4) v = *(const uint4*)(hIn + (size_t)node*TIN*32 + l*8);
  for(; node < NN; node += stride){
    if(l < TIN*4){
      int ts = l >> 2, cb = (l & 3)*8;
      if(BNIN){
        unsigned short tmp[8];
        const unsigned short* up = (const unsigned short*)&v;
#pragma unroll
        for(int j=0;j<8;j++) tmp[j] = f2bf((bf2f(up[j]) - sm[j])*sv[j]);
        *(uint4*)(hw + ts*RS + cb) = *(const uint4*)tmp;
      } else {
        *(uint4*)(hw + ts*RS + cb) = v;
      }
    }
    int nn2 = node + stride;
    if(nn2 < NN && l < TIN*4) v = *(const uint4*)(hIn + (size_t)nn2*TIN*32 + l*8);
    bf16x8 a0 = *(const bf16x8*)(hw + tr*RS + quad*8);
    bf16x8 a1 = *(const bf16x8*)(hw + (tr+D)*RS + quad*8);
    f32x4 accf[2], accg[2];
#pragma unroll
    for(int i=0;i<2;i++){ accf[i] = (f32x4){0.f,0.f,0.f,0.f}; accg[i] = (f32x4){0.f,0.f,0.f,0.f}; }
#pragma unroll
    for(int i=0;i<2;i++){
      accf[i] = __builtin_amdgcn_mfma_f32_16x16x32_bf16(a0, bwf[0][i], accf[i], 0,0,0);
      accf[i] = __builtin_amdgcn_mfma_f32_16x16x32_bf16(a1, bwf[1][i], accf[i], 0,0,0);
      accg[i] = __builtin_amdgcn_mfma_f32_16x16x32_bf16(a0, bwg[0][i], accg[i], 0,0,0);
      accg[i] = __builtin_amdgcn_mfma_f32_16x16x32_bf16(a1, bwg[1][i], accg[i], 0,0,0);
    }
#pragma unroll
    for(int i=0;i<2;i++){
      int cout = 16*i + tcol;
#pragma unroll
      for(int r=0;r<4;r++){
        int t = quad*4 + r;
        if(t < TOUT){
          float f = accf[i][r] + fbv[i];
          float g = accg[i][r] + gbv[i];
          float gated = ftanh(f)*fsig(g);
          if(t == TOUT-1) gl[(size_t)node*256 + cout] = f2bf(gated);
          float outv = gated + bf2f(hw[(t+D)*RS + cout]);
          if(WRITEH) how[t*RS + cout] = f2bf(outv);
          if(STATS){ sA[i] += outv; s2A[i] += outv*outv; }
        }
      }
    }
    if(WRITEH && l < TOUT*4){
      int to = l >> 2, cb = (l & 3)*8;
      *(uint4*)(hOut + (size_t)node*TOUT*32 + to*32 + cb) = *(const uint4*)(how + to*RS + cb);
    }
  }
  if(STATS){
#pragma unroll
    for(int i=0;i<2;i++){
      sA[i]  += __shfl_xor(sA[i], 16);  sA[i]  += __shfl_xor(sA[i], 32);
      s2A[i] += __shfl_xor(s2A[i], 16); s2A[i] += __shfl_xor(s2A[i], 32);
    }
    if(l < 16){
#pragma unroll
      for(int i=0;i<2;i++){
        atomicAdd(&bnred[16*i + l], sA[i]);
        atomicAdd(&bnred[32 + 16*i + l], s2A[i]);
      }
    }
    __syncthreads();
    if(tid < 64) atomicAdd(&bnOut[tid], bnred[tid]);
  }
}

// ---------------- final ----------------
__global__ __launch_bounds__(256) void k_final(const float* __restrict__ skip,
    const float* __restrict__ Wc, const float* __restrict__ bc,
    const float* __restrict__ stdev, const float* __restrict__ means,
    float* __restrict__ out){
  __shared__ float wsm[3072];
  __shared__ float bcs[12];
  int tid = threadIdx.x;
  for(int j = tid; j < 3072; j += 256){
    int c = j / 12, k = j - c*12;
    wsm[c*12 + k] = Wc[k*256 + c];
  }
  if(tid < 12) bcs[tid] = bc[tid];
  __syncthreads();
  int idx = blockIdx.x*256 + tid;
  if(idx >= NN*12) return;
  int n = idx / 12, k = idx - n*12;
  const float* sr = skip + (size_t)n*256;
  float acc = bcs[k];
#pragma unroll 8
  for(int c = 0; c < 256; c++) acc += wsm[c*12 + k]*fmaxf(sr[c], 0.f);
  out[idx] = acc*stdev[n] + means[n];
}

extern "C" void kernel_launch(void* const* d_in, const int* in_sizes, int n_in,
                              void* d_out, int out_size, void* d_ws, size_t ws_size,
                              hipStream_t stream) {
  const float* x      = (const float*)d_in[0];
  const int*   ei     = (const int*)  d_in[1];
  const float* ea     = (const float*)d_in[2];
  const float* startW = (const float*)d_in[3];
  const float* startb = (const float*)d_in[4];
  const float* fW     = (const float*)d_in[5];
  const float* fb     = (const float*)d_in[6];
  const float* gW     = (const float*)d_in[7];
  const float* gb     = (const float*)d_in[8];
  const float* sW     = (const float*)d_in[9];
  const float* sb     = (const float*)d_in[10];
  const float* g0W0   = (const float*)d_in[11];
  const float* g0W1   = (const float*)d_in[12];
  const float* g0b    = (const float*)d_in[13];
  const float* g1W0   = (const float*)d_in[14];
  const float* g1W1   = (const float*)d_in[15];
  const float* g1b    = (const float*)d_in[16];
  const float* e1W    = (const float*)d_in[17];
  const float* e1b    = (const float*)d_in[18];
  const float* e2W    = (const float*)d_in[19];
  const float* e2b    = (const float*)d_in[20];
  float* out = (float*)d_out;
  float* ws  = (float*)d_ws;

  const int MP = 20096;
  size_t o = 0;
  unsigned short* hA = (unsigned short*)(ws + o); o += (size_t)NN*208;   // bf16 [NN][13*32]
  unsigned short* hB = (unsigned short*)(ws + o); o += (size_t)NN*208;
  unsigned short* Acat  = (unsigned short*)(ws + o); o += (size_t)MP*384;  // bf16 [MP][768]
  unsigned short* glcat = (unsigned short*)(ws + o); o += (size_t)MP*128;  // bf16 [MP][256]
  unsigned short* Wt0 = (unsigned short*)(ws + o); o += 147456;
  unsigned short* Wt1 = (unsigned short*)(ws + o); o += 36864;
  unsigned short* Bwt = (unsigned short*)(ws + o); o += 32768;
  unsigned short* Wfrag = (unsigned short*)(ws + o); o += 16384;   // 8 layers x 4096 ushorts
  float* Bfrag = ws + o; o += 2048;                                 // 8 layers x 256 floats
  float* bP0   = ws + o; o += 384;
  float* bP1   = ws + o; o += 192;
  float* bias2 = ws + o; o += 256;
  float* Wc    = ws + o; o += 3072;
  float* bc    = ws + o; o += 16;
  float* stdev = ws + o; o += NN;
  float* means = ws + o; o += NN;
  float* xc    = ws + o; o += (size_t)NN*TT;
  float* deg   = ws + o; o += NN;            // deg, cnt, bnstats contiguous -> one memset
  int*   cnt   = (int*)(ws + o); o += NN;
  float* bnstats = ws + o; o += 512;
  float* normb = ws + o; o += NE;
  int*   rowArr = (int*)(ws + o); o += NE;
  float* nrmArr = ws + o; o += NE;
  int*   rowptr = (int*)(ws + o); o += NN + 4;
  int*   woff   = (int*)(ws + o); o += NN;
  float* skipb  = (float*)hA;                // overlay: hA+hB dead by skip-GEMM time

  hipMemsetAsync(deg, 0, (2*NN + 512)*sizeof(float), stream);
  k_instnorm<<<(NN+255)/256, 256, 0, stream>>>(x, xc, stdev, means);
  k_start2<<<((NN*TT*16)+255)/256, 256, 0, stream>>>(xc, startW, startb, hA);
  k_deg<<<(NE+255)/256, 256, 0, stream>>>(ei, ea, deg);
  k_dinv<<<(NN+255)/256, 256, 0, stream>>>(deg);
  k_normcount<<<(NE+255)/256, 256, 0, stream>>>(ei, ea, deg, normb, cnt);
  k_scan<<<1, 1024, 0, stream>>>(cnt, rowptr, woff);
  k_place<<<(NE+255)/256, 256, 0, stream>>>(normb, ei, woff, rowArr, nrmArr);
  k_prep2<<<256, 256, 0, stream>>>(sW, sb, Bwt, bias2);
  k_comb<<<12, 256, 0, stream>>>(e1W, e1b, e2W, e2b, Wc, bc);
  k_prepw2<<<(384*768+255)/256, 256, 0, stream>>>(g0W0, g0W1, g0b, Wt0, bP0, 384, 768, 12);
  k_prepw2<<<(192*384+255)/256, 256, 0, stream>>>(g1W0, g1W1, g1b, Wt1, bP1, 192, 384, 6);
  k_prepg<<<128, 256, 0, stream>>>(fW, fb, gW, gb, Wfrag, Bfrag);

  const int GB = 1280;
  // L0: hA -> hB
  k_gated4<1,13,12,false,true,true><<<GB,256,0,stream>>>(hA, hB, glcat+0,
      bnstats, bnstats+0, Wfrag, Bfrag, 0, 0.f);
  // GCN0: BN(hB) -> Acat ; gather ; GEMM -> hA (T=12)
  k_cvtbn2<<<((NN*192)+255)/256, 256, 0, stream>>>(hB, bnstats+0, 1.f/(NN*12.f), Acat, 384, 768);
  k_gather2<<<NN, 192, 0, stream>>>(Acat, 768, 384, 192, rowArr, nrmArr, rowptr, Acat);
  { dim3 g(MP/128, 384/64);
    k_gemm_bf16<true><<<g, 256, 0, stream>>>(Acat, Wt0, bP0, hA, NN, 384, 768); }
  // L1: hA -> hB
  k_gated4<2,12,10,false,true,true><<<GB,256,0,stream>>>(hA, hB, glcat+32,
      bnstats, bnstats+64, Wfrag, Bfrag, 1, 0.f);
  // L2: hB -> hA
  k_gated4<1,10,9,true,true,true><<<GB,256,0,stream>>>(hB, hA, glcat+64,
      bnstats+64, bnstats+128, Wfrag, Bfrag, 2, 1.f/(NN*10.f));
  // L3: hA -> hB
  k_gated4<2,9,7,true,true,true><<<GB,256,0,stream>>>(hA, hB, glcat+96,
      bnstats+128, bnstats+192, Wfrag, Bfrag, 3, 1.f/(NN*9.f));
  // L4: hB -> hA
  k_gated4<1,7,6,true,true,true><<<GB,256,0,stream>>>(hB, hA, glcat+128,
      bnstats+192, bnstats+256, Wfrag, Bfrag, 4, 1.f/(NN*7.f));
  // GCN1: BN(hA) -> Acat ; gather ; GEMM -> hB (T=6)
  k_cvtbn2<<<((NN*96)+255)/256, 256, 0, stream>>>(hA, bnstats+256, 1.f/(NN*6.f), Acat, 192, 384);
  k_gather2<<<NN, 128, 0, stream>>>(Acat, 384, 192, 96, rowArr, nrmArr, rowptr, Acat);
  { dim3 g(MP/128, 192/64);
    k_gemm_bf16<true><<<g, 256, 0, stream>>>(Acat, Wt1, bP1, hB, NN, 192, 384); }
  // L5: hB -> hA
  k_gated4<2,6,4,false,true,true><<<GB,256,0,stream>>>(hB, hA, glcat+160,
      bnstats, bnstats+320, Wfrag, Bfrag, 5, 0.f);
  // L6: hA -> hB
  k_gated4<1,4,3,true,true,true><<<GB,256,0,stream>>>(hA, hB, glcat+192,
      bnstats+320, bnstats+384, Wfrag, Bfrag, 6, 1.f/(NN*4.f));
  // L7: hB -> (gl only)
  k_gated4<2,3,1,true,false,false><<<GB,256,0,stream>>>(hB, nullptr, glcat+224,
      bnstats+384, bnstats+448, Wfrag, Bfrag, 7, 1.f/(NN*3.f));

  // skip GEMM (fp32 out): skipb[N,256] = glcat @ Bwt^T + bias2
  { dim3 g(MP/128, 256/64);
    k_gemm_bf16<false><<<g, 256, 0, stream>>>(glcat, Bwt, bias2, skipb, NN, 256, 256); }
  k_final<<<((NN*12)+255)/256, 256, 0, stream>>>(skipb, Wc, bc, stdev, means, out);
}

// Round 6
// 460.711 us; speedup vs baseline: 6.5924x; 1.3423x over previous
//
#include <hip/hip_runtime.h>
#include <math.h>

#define NN 20000
#define NE 200000
#define TT 13
#define NBLK 79   // ceil(NN/256)

typedef short bf16x8 __attribute__((ext_vector_type(8)));
typedef float f32x4 __attribute__((ext_vector_type(4)));

__device__ inline unsigned short f2bf(float f){
  union{float f; unsigned u;} v; v.f = f;
  unsigned r = v.u + 0x7fffu + ((v.u >> 16) & 1u);
  return (unsigned short)(r >> 16);
}
__device__ inline float bf2f(unsigned short h){
  union{unsigned u; float f;} v; v.u = ((unsigned)h) << 16; return v.f;
}
__device__ inline float fsig(float x){ return __builtin_amdgcn_rcpf(1.f + __expf(-x)); }
__device__ inline float ftanh(float x){ return 2.f*__builtin_amdgcn_rcpf(1.f + __expf(-2.f*x)) - 1.f; }

// ---------------- instance norm (over time) ----------------
__global__ __launch_bounds__(256) void k_instnorm(const float* __restrict__ x,
    float* __restrict__ xc, float* __restrict__ stdev, float* __restrict__ means){
  int n = blockIdx.x*256 + threadIdx.x;
  if(n >= NN) return;
  float v[TT]; float s = 0.f;
#pragma unroll
  for(int t=0;t<TT;t++){ v[t] = x[n*TT+t]; s += v[t]; }
  float m = s * (1.0f/TT);
  float s2 = 0.f;
#pragma unroll
  for(int t=0;t<TT;t++){ v[t] -= m; s2 += v[t]*v[t]; }
  float sd = sqrtf(s2*(1.0f/TT) + 1e-5f);
  float inv = 1.0f/sd;
#pragma unroll
  for(int t=0;t<TT;t++) xc[n*TT+t] = v[t]*inv;
  stdev[n] = sd; means[n] = m;
}

// ---------------- start conv -> bf16 h[n][t][c] ----------------
__global__ __launch_bounds__(256) void k_start2(const float* __restrict__ xc,
    const float* __restrict__ sW, const float* __restrict__ sb, unsigned short* __restrict__ h){
  int idx = blockIdx.x*256 + threadIdx.x;
  if(idx >= NN*TT*16) return;
  int cp = idx & 15; int t = (idx >> 4) % TT; int n = idx/(16*TT);
  float xv = xc[n*TT+t];
  int c0 = cp*2;
  unsigned u = (unsigned)f2bf(sW[c0]*xv + sb[c0]) | ((unsigned)f2bf(sW[c0+1]*xv + sb[c0+1]) << 16);
  *(unsigned*)(h + (size_t)n*TT*32 + t*32 + c0) = u;
}

// ---------------- GCN edge-norm precompute ----------------
__global__ __launch_bounds__(256) void k_deg(const int* __restrict__ ei,
    const float* __restrict__ ea, float* __restrict__ deg){
  int e = blockIdx.x*256 + threadIdx.x;
  if(e >= NE) return;
  int r = ei[e], c = ei[NE+e];
  float w = (r==c) ? 0.f : ea[e];
  if(w != 0.f) atomicAdd(&deg[r], w);
}

__global__ __launch_bounds__(256) void k_dinv(float* __restrict__ deg){
  int n = blockIdx.x*256 + threadIdx.x;
  if(n >= NN) return;
  float d = deg[n];
  deg[n] = (d > 0.f) ? rsqrtf(d) : 0.f;
}

__global__ __launch_bounds__(256) void k_normcount(const int* __restrict__ ei,
    const float* __restrict__ ea, const float* __restrict__ dinv,
    float* __restrict__ nrm, int* __restrict__ cnt){
  int e = blockIdx.x*256 + threadIdx.x;
  if(e >= NE) return;
  int r = ei[e], c = ei[NE+e];
  float w = (r==c) ? 0.f : ea[e];
  float nv = dinv[r]*w*dinv[c];
  nrm[e] = nv;
  if(nv != 0.f) atomicAdd(&cnt[c], 1);
}

// ---------------- two-level scan ----------------
__global__ __launch_bounds__(256) void k_scanA(const int* __restrict__ cnt, int* __restrict__ bsum){
  int i = blockIdx.x*256 + threadIdx.x;
  int l = threadIdx.x & 63, w = threadIdx.x >> 6;
  int v = (i < NN) ? cnt[i] : 0;
#pragma unroll
  for(int off = 1; off < 64; off <<= 1) v += __shfl_xor(v, off);
  __shared__ int ws4[4];
  if(l == 0) ws4[w] = v;
  __syncthreads();
  if(threadIdx.x == 0) bsum[blockIdx.x] = ws4[0]+ws4[1]+ws4[2]+ws4[3];
}

__global__ __launch_bounds__(128) void k_scanB(const int* __restrict__ bsum, int* __restrict__ bbase){
  __shared__ int buf[128];
  int t = threadIdx.x;
  int v = (t < NBLK) ? bsum[t] : 0;
  buf[t] = v; __syncthreads();
  for(int off = 1; off < 128; off <<= 1){
    int u = (t >= off) ? buf[t-off] : 0;
    __syncthreads();
    buf[t] += u;
    __syncthreads();
  }
  if(t < NBLK) bbase[t] = buf[t] - v;
  if(t == NBLK-1) bbase[NBLK] = buf[t];
}

__global__ __launch_bounds__(256) void k_scanC(const int* __restrict__ cnt,
    const int* __restrict__ bbase, int* __restrict__ rowptr, int* __restrict__ woff){
  int i = blockIdx.x*256 + threadIdx.x;
  int t = threadIdx.x, l = t & 63, w = t >> 6;
  int v = (i < NN) ? cnt[i] : 0;
  int x = v;
#pragma unroll
  for(int off = 1; off < 64; off <<= 1){
    int u = __shfl_up(x, off);
    if(l >= off) x += u;
  }
  __shared__ int wt[4];
  if(l == 63) wt[w] = x;
  __syncthreads();
  int wo = 0;
  for(int k = 0; k < w; k++) wo += wt[k];
  int excl = bbase[blockIdx.x] + wo + x - v;
  if(i < NN){ rowptr[i] = excl; woff[i] = excl; }
  if(i == 0) rowptr[NN] = bbase[NBLK];
}

__global__ __launch_bounds__(256) void k_place(const float* __restrict__ nrm,
    const int* __restrict__ ei, int* __restrict__ woff,
    int* __restrict__ rowArr, float* __restrict__ nrmArr){
  int e = blockIdx.x*256 + threadIdx.x;
  if(e >= NE) return;
  float nv = nrm[e];
  if(nv == 0.f) return;
  int c = ei[NE+e];
  int pos = atomicAdd(&woff[c], 1);
  rowArr[pos] = ei[e];
  nrmArr[pos] = nv;
}

// ---------------- fold 16 stat buckets -> 64 floats ----------------
__global__ __launch_bounds__(64) void k_bnfold(const float* __restrict__ in, float* __restrict__ out){
  int t = threadIdx.x;
  float s = 0.f;
#pragma unroll
  for(int b = 0; b < 16; b++) s += in[b*64 + t];
  out[t] = s;
}

// ---------------- fused prep: all weight re-layouts in one dispatch ----------------
__device__ inline void d_prepw2(const float* W0, const float* W1, const float* b,
    unsigned short* Wt, float* bPerm, int F, int Kp, int T, int idx){
  if(idx >= F*Kp) return;
  int o = idx / Kp, k = idx - o*Kp;
  int to = o >> 5, co = o & 31; int fout = co*T + to;
  int ki = (k < F) ? k : k - F;
  int ti = ki >> 5, ci = ki & 31; int fin = ci*T + ti;
  float v = (k < F) ? W0[fin*F + fout] : W1[fin*F + fout];
  Wt[idx] = f2bf(v);
  if(k == 0) bPerm[o] = b[fout];
}
__device__ inline void d_prep2(const float* sW, const float* sb,
    unsigned short* Bwt, float* b2, int idx){
  if(idx >= 65536) return;
  int sOut = idx >> 8; int ic = idx & 255; int i = ic >> 5; int c = ic & 31;
  Bwt[idx] = f2bf(sW[i*8192 + sOut*32 + c]);
  if(idx < 256){
    float acc = 0.f;
    for(int ll = 0; ll < 8; ll++) acc += sb[ll*256 + idx];
    b2[idx] = acc;
  }
}
__device__ inline void d_comb(const float* e1W, const float* e1b,
    const float* e2W, const float* e2b, float* Wc, float* bc, int idx){
  if(idx >= 12*256) return;
  int k = idx >> 8, c = idx & 255;
  float acc = 0.f;
  for(int o = 0; o < 512; o++) acc += e2W[k*512+o]*e1W[o*256+c];
  Wc[idx] = acc;
  if(c == 0){
    float b = e2b[k];
    for(int o = 0; o < 512; o++) b += e2W[k*512+o]*e1b[o];
    bc[k] = b;
  }
}
__device__ inline void d_prepg(const float* fW, const float* fb,
    const float* gW, const float* gb, unsigned short* Wfrag, float* Bfrag, int idx){
  if(idx < 8*8*64*8){
    int j = idx & 7; int lane = (idx >> 3) & 63; int chunk = (idx >> 9) & 7; int layer = idx >> 12;
    int fg = chunk >> 2; int q = (chunk >> 1) & 1; int i = chunk & 1;
    int quad = lane >> 4, tcol = lane & 15;
    int cout = 16*i + tcol, cin = quad*8 + j;
    const float* W = fg ? gW : fW;
    Wfrag[idx] = f2bf(W[layer*2048 + cout*64 + cin*2 + q]);
  }
  if(idx < 8*64*4){
    int r = idx & 3; int lane = (idx >> 2) & 63; int layer = idx >> 8;
    int tcol = lane & 15;
    float v;
    if(r == 0)      v = fb[layer*32 + tcol];
    else if(r == 1) v = fb[layer*32 + 16 + tcol];
    else if(r == 2) v = gb[layer*32 + tcol];
    else            v = gb[layer*32 + 16 + tcol];
    Bfrag[idx] = v;
  }
}
__global__ __launch_bounds__(256) void k_prepall(
    const float* g0W0, const float* g0W1, const float* g0b,
    const float* g1W0, const float* g1W1, const float* g1b,
    const float* sW, const float* sb,
    const float* e1W, const float* e1b, const float* e2W, const float* e2b,
    const float* fW, const float* fb, const float* gW, const float* gb,
    unsigned short* Wt0, float* bP0, unsigned short* Wt1, float* bP1,
    unsigned short* Bwt, float* bias2, float* Wc, float* bc,
    unsigned short* Wfrag, float* Bfrag){
  int b = blockIdx.x, t = threadIdx.x;
  if(b < 1152)       d_prepw2(g0W0, g0W1, g0b, Wt0, bP0, 384, 768, 12, b*256 + t);
  else if(b < 1440)  d_prepw2(g1W0, g1W1, g1b, Wt1, bP1, 192, 384, 6, (b-1152)*256 + t);
  else if(b < 1696)  d_prep2(sW, sb, Bwt, bias2, (b-1440)*256 + t);
  else if(b < 1708)  d_comb(e1W, e1b, e2W, e2b, Wc, bc, (b-1696)*256 + t);
  else               d_prepg(fW, fb, gW, gb, Wfrag, Bfrag, (b-1708)*256 + t);
}

// ---------------- BN-apply (bf16->bf16) into Acat first half ----------------
__global__ __launch_bounds__(256) void k_cvtbn2(const unsigned short* __restrict__ h,
    const float* __restrict__ bn, float cntInv, unsigned short* __restrict__ A,
    int F, int Kp){
  int idx = blockIdx.x*256 + threadIdx.x;
  int half = F >> 1;
  if(idx >= NN*half) return;
  int n = idx / half, r = idx - n*half;
  int k0 = 2*r; int c0 = k0 & 31;
  unsigned u = *(const unsigned*)(h + (size_t)n*F + k0);
  float m0 = bn[c0]*cntInv, m1 = bn[c0+1]*cntInv;
  float i0 = rsqrtf(bn[32+c0]*cntInv - m0*m0 + 1e-5f);
  float i1 = rsqrtf(bn[32+c0+1]*cntInv - m1*m1 + 1e-5f);
  float v0 = (bf2f((unsigned short)(u & 0xffffu)) - m0)*i0;
  float v1 = (bf2f((unsigned short)(u >> 16)) - m1)*i1;
  unsigned outw = (unsigned)f2bf(v0) | ((unsigned)f2bf(v1) << 16);
  *(unsigned*)(A + (size_t)n*Kp + k0) = outw;
}

// ---------------- gather SpMM (bf16) ----------------
__global__ void k_gather2(const unsigned short* __restrict__ Acat, int Kp, int F, int F2,
    const int* __restrict__ rowArr, const float* __restrict__ nrmArr,
    const int* __restrict__ rowptr, unsigned short* __restrict__ dst){
  int node = blockIdx.x;
  int f2 = threadIdx.x;
  int beg = rowptr[node], end = rowptr[node+1];
  __shared__ int srow[64];
  __shared__ float snrm[64];
  float a0 = 0.f, a1 = 0.f;
  for(int base = beg; base < end; base += 64){
    int m = end - base; if(m > 64) m = 64;
    __syncthreads();
    if(threadIdx.x < m){ srow[threadIdx.x] = rowArr[base+threadIdx.x]; snrm[threadIdx.x] = nrmArr[base+threadIdx.x]; }
    __syncthreads();
    if(f2 < F2){
      for(int j = 0; j < m; j++){
        unsigned u = *(const unsigned*)(Acat + (size_t)srow[j]*Kp + 2*f2);
        float nv = snrm[j];
        a0 += nv*bf2f((unsigned short)(u & 0xffffu));
        a1 += nv*bf2f((unsigned short)(u >> 16));
      }
    }
  }
  if(f2 < F2){
    unsigned outw = (unsigned)f2bf(-a0) | ((unsigned)f2bf(-a1) << 16);
    *(unsigned*)(dst + (size_t)node*Kp + F + 2*f2) = outw;
  }
}

// ---------------- bf16 MFMA GEMM: C = A[M][K] @ Bt[N][K]^T + bias ----------------
template<bool BOUT>
__global__ __launch_bounds__(256) void k_gemm_bf16(const unsigned short* __restrict__ A,
    const unsigned short* __restrict__ Bt, const float* __restrict__ bias,
    void* __restrict__ Cv, int M, int N, int K){
  __shared__ unsigned short As[128*32];
  __shared__ unsigned short Bs[64*32];
  int tid = threadIdx.x;
  int w = tid >> 6, l = tid & 63, quad = l >> 4, tcol = l & 15;
  int m0 = blockIdx.x*128, n0 = blockIdx.y*64;
  int rw = (w & 1)*64, cw = (w >> 1)*32;
  int sr = tid >> 2, sc = (tid & 3)*8;
  f32x4 acc[4][2];
#pragma unroll
  for(int i=0;i<4;i++)
#pragma unroll
    for(int j=0;j<2;j++) acc[i][j] = (f32x4){0.f,0.f,0.f,0.f};
  for(int k0 = 0; k0 < K; k0 += 32){
    uint4 a0 = *(const uint4*)(A + (size_t)(m0 + sr)*K + k0 + sc);
    uint4 a1 = *(const uint4*)(A + (size_t)(m0 + 64 + sr)*K + k0 + sc);
    uint4 b0 = *(const uint4*)(Bt + (size_t)(n0 + sr)*K + k0 + sc);
    __syncthreads();
    *(uint4*)(As + sr*32 + sc) = a0;
    *(uint4*)(As + (64+sr)*32 + sc) = a1;
    *(uint4*)(Bs + sr*32 + sc) = b0;
    __syncthreads();
    bf16x8 av[4], bv[2];
#pragma unroll
    for(int i=0;i<4;i++) av[i] = *(const bf16x8*)(As + (rw + 16*i + tcol)*32 + quad*8);
#pragma unroll
    for(int j=0;j<2;j++) bv[j] = *(const bf16x8*)(Bs + (cw + 16*j + tcol)*32 + quad*8);
#pragma unroll
    for(int i=0;i<4;i++)
#pragma unroll
      for(int j=0;j<2;j++)
        acc[i][j] = __builtin_amdgcn_mfma_f32_16x16x32_bf16(av[i], bv[j], acc[i][j], 0, 0, 0);
  }
#pragma unroll
  for(int i=0;i<4;i++){
#pragma unroll
    for(int j=0;j<2;j++){
      int col = n0 + cw + 16*j + tcol;
      float bb = bias[col];
#pragma unroll
      for(int r=0;r<4;r++){
        int row = m0 + rw + 16*i + quad*4 + r;
        if(row < M){
          float o = acc[i][j][r] + bb;
          if(BOUT) ((unsigned short*)Cv)[(size_t)row*N + col] = f2bf(o);
          else ((float*)Cv)[(size_t)row*N + col] = o;
        }
      }
    }
  }
}

// ---------------- fused gated conv; wave = 8 contiguous nodes, 2-node ILP ----------------
template<int D,int TIN,int TOUT,bool BNIN,bool STATS,bool WRITEH>
__global__ __launch_bounds__(256) void k_gated5(
    const unsigned short* __restrict__ hIn, unsigned short* __restrict__ hOut,
    unsigned short* __restrict__ gl,
    const float* __restrict__ bnIn, float* __restrict__ bnOut,
    const unsigned short* __restrict__ Wfrag, const float* __restrict__ Bfrag,
    int layer, float cntInv){
  constexpr int RS = 40;
  __shared__ unsigned short hs[4][2][TIN*RS];
  __shared__ unsigned short ho[4][2][WRITEH ? TOUT*RS : RS];
  __shared__ float bnm[32], bnv[32];
  __shared__ float bnred[64];
  int tid = threadIdx.x;
  int w = tid >> 6, l = tid & 63, quad = l >> 4, tcol = l & 15;
  if(BNIN && tid < 32){
    float s = 0.f, s2 = 0.f;
#pragma unroll
    for(int b = 0; b < 16; b++){ s += bnIn[b*64 + tid]; s2 += bnIn[b*64 + 32 + tid]; }
    float m = s*cntInv;
    float var = s2*cntInv - m*m;
    bnm[tid] = m; bnv[tid] = rsqrtf(var + 1e-5f);
  }
  if(STATS && tid < 64) bnred[tid] = 0.f;
  __syncthreads();
  float sm[8], sv[8];
  if(BNIN){
    int cb = (l & 3)*8;
#pragma unroll
    for(int j=0;j<8;j++){ sm[j] = bnm[cb+j]; sv[j] = bnv[cb+j]; }
  }
  // coalesced weight fragment preload
  const unsigned short* wfr = Wfrag + layer*4096;
  bf16x8 bwf[2][2], bwg[2][2];
#pragma unroll
  for(int q=0;q<2;q++)
#pragma unroll
    for(int i=0;i<2;i++){
      bwf[q][i] = *(const bf16x8*)(wfr + ((q*2+i)*64 + l)*8);
      bwg[q][i] = *(const bf16x8*)(wfr + ((4 + q*2+i)*64 + l)*8);
    }
  float4 bv4 = *(const float4*)(Bfrag + layer*256 + l*4);
  float fbv[2] = {bv4.x, bv4.y}, gbv[2] = {bv4.z, bv4.w};

  int tr = (tcol < TOUT) ? tcol : 0;
  unsigned short* hwA = hs[w][0];
  unsigned short* hwB = hs[w][1];
  unsigned short* howA = ho[w][0];
  unsigned short* howB = ho[w][1];
  float sA[2] = {0.f,0.f}, s2A[2] = {0.f,0.f};
  int wid = blockIdx.x*4 + w;
  int base = wid*8;
  bool ldact = (l < TIN*4);
  int ts = l >> 2, cb = (l & 3)*8;
  uint4 vA = {0,0,0,0}, vB = {0,0,0,0};
  if(ldact && base < NN){
    vA = *(const uint4*)(hIn + (size_t)base*TIN*32 + l*8);
    vB = *(const uint4*)(hIn + (size_t)(base+1)*TIN*32 + l*8);
  }
  for(int p = 0; p < 4; p++){
    int nA = base + 2*p;
    if(nA >= NN) break;
    int nB = nA + 1;
    if(ldact){
      if(BNIN){
        unsigned short tA[8], tB[8];
        const unsigned short* uA = (const unsigned short*)&vA;
        const unsigned short* uB = (const unsigned short*)&vB;
#pragma unroll
        for(int j=0;j<8;j++){
          tA[j] = f2bf((bf2f(uA[j]) - sm[j])*sv[j]);
          tB[j] = f2bf((bf2f(uB[j]) - sm[j])*sv[j]);
        }
        *(uint4*)(hwA + ts*RS + cb) = *(const uint4*)tA;
        *(uint4*)(hwB + ts*RS + cb) = *(const uint4*)tB;
      } else {
        *(uint4*)(hwA + ts*RS + cb) = vA;
        *(uint4*)(hwB + ts*RS + cb) = vB;
      }
    }
    // prefetch next pair
    if(p < 3 && ldact && nA + 2 < NN){
      vA = *(const uint4*)(hIn + (size_t)(nA+2)*TIN*32 + l*8);
      vB = *(const uint4*)(hIn + (size_t)(nA+3)*TIN*32 + l*8);
    }
    bf16x8 aA0 = *(const bf16x8*)(hwA + tr*RS + quad*8);
    bf16x8 aA1 = *(const bf16x8*)(hwA + (tr+D)*RS + quad*8);
    bf16x8 aB0 = *(const bf16x8*)(hwB + tr*RS + quad*8);
    bf16x8 aB1 = *(const bf16x8*)(hwB + (tr+D)*RS + quad*8);
    f32x4 afA[2], agA[2], afB[2], agB[2];
#pragma unroll
    for(int i=0;i<2;i++){
      afA[i] = (f32x4){0.f,0.f,0.f,0.f}; agA[i] = afA[i];
      afB[i] = afA[i]; agB[i] = afA[i];
    }
#pragma unroll
    for(int i=0;i<2;i++){
      afA[i] = __builtin_amdgcn_mfma_f32_16x16x32_bf16(aA0, bwf[0][i], afA[i], 0,0,0);
      afB[i] = __builtin_amdgcn_mfma_f32_16x16x32_bf16(aB0, bwf[0][i], afB[i], 0,0,0);
      afA[i] = __builtin_amdgcn_mfma_f32_16x16x32_bf16(aA1, bwf[1][i], afA[i], 0,0,0);
      afB[i] = __builtin_amdgcn_mfma_f32_16x16x32_bf16(aB1, bwf[1][i], afB[i], 0,0,0);
      agA[i] = __builtin_amdgcn_mfma_f32_16x16x32_bf16(aA0, bwg[0][i], agA[i], 0,0,0);
      agB[i] = __builtin_amdgcn_mfma_f32_16x16x32_bf16(aB0, bwg[0][i], agB[i], 0,0,0);
      agA[i] = __builtin_amdgcn_mfma_f32_16x16x32_bf16(aA1, bwg[1][i], agA[i], 0,0,0);
      agB[i] = __builtin_amdgcn_mfma_f32_16x16x32_bf16(aB1, bwg[1][i], agB[i], 0,0,0);
    }
#pragma unroll
    for(int i=0;i<2;i++){
      int cout = 16*i + tcol;
#pragma unroll
      for(int r=0;r<4;r++){
        int t = quad*4 + r;
        if(t < TOUT){
          float fA = afA[i][r] + fbv[i];
          float gA = agA[i][r] + gbv[i];
          float fB = afB[i][r] + fbv[i];
          float gB = agB[i][r] + gbv[i];
          float gatedA = ftanh(fA)*fsig(gA);
          float gatedB = ftanh(fB)*fsig(gB);
          if(t == TOUT-1){
            gl[(size_t)nA*256 + cout] = f2bf(gatedA);
            gl[(size_t)nB*256 + cout] = f2bf(gatedB);
          }
          float oA = gatedA + bf2f(hwA[(t+D)*RS + cout]);
          float oB = gatedB + bf2f(hwB[(t+D)*RS + cout]);
          if(WRITEH){ howA[t*RS + cout] = f2bf(oA); howB[t*RS + cout] = f2bf(oB); }
          if(STATS){ sA[i] += oA + oB; s2A[i] += oA*oA + oB*oB; }
        }
      }
    }
    if(WRITEH && l < TOUT*4){
      int to = l >> 2, cb2 = (l & 3)*8;
      *(uint4*)(hOut + (size_t)nA*TOUT*32 + to*32 + cb2) = *(const uint4*)(howA + to*RS + cb2);
      *(uint4*)(hOut + (size_t)nB*TOUT*32 + to*32 + cb2) = *(const uint4*)(howB + to*RS + cb2);
    }
  }
  if(STATS){
#pragma unroll
    for(int i=0;i<2;i++){
      sA[i]  += __shfl_xor(sA[i], 16);  sA[i]  += __shfl_xor(sA[i], 32);
      s2A[i] += __shfl_xor(s2A[i], 16); s2A[i] += __shfl_xor(s2A[i], 32);
    }
    if(l < 16){
#pragma unroll
      for(int i=0;i<2;i++){
        atomicAdd(&bnred[16*i + l], sA[i]);
        atomicAdd(&bnred[32 + 16*i + l], s2A[i]);
      }
    }
    __syncthreads();
    if(tid < 64) atomicAdd(&bnOut[(blockIdx.x & 15)*64 + tid], bnred[tid]);
  }
}

// ---------------- final ----------------
__global__ __launch_bounds__(256) void k_final(const float* __restrict__ skip,
    const float* __restrict__ Wc, const float* __restrict__ bc,
    const float* __restrict__ stdev, const float* __restrict__ means,
    float* __restrict__ out){
  __shared__ float wsm[3072];
  __shared__ float bcs[12];
  int tid = threadIdx.x;
  for(int j = tid; j < 3072; j += 256){
    int c = j / 12, k = j - c*12;
    wsm[c*12 + k] = Wc[k*256 + c];
  }
  if(tid < 12) bcs[tid] = bc[tid];
  __syncthreads();
  int idx = blockIdx.x*256 + tid;
  if(idx >= NN*12) return;
  int n = idx / 12, k = idx - n*12;
  const float* sr = skip + (size_t)n*256;
  float acc = bcs[k];
#pragma unroll 8
  for(int c = 0; c < 256; c++) acc += wsm[c*12 + k]*fmaxf(sr[c], 0.f);
  out[idx] = acc*stdev[n] + means[n];
}

extern "C" void kernel_launch(void* const* d_in, const int* in_sizes, int n_in,
                              void* d_out, int out_size, void* d_ws, size_t ws_size,
                              hipStream_t stream) {
  const float* x      = (const float*)d_in[0];
  const int*   ei     = (const int*)  d_in[1];
  const float* ea     = (const float*)d_in[2];
  const float* startW = (const float*)d_in[3];
  const float* startb = (const float*)d_in[4];
  const float* fW     = (const float*)d_in[5];
  const float* fb     = (const float*)d_in[6];
  const float* gW     = (const float*)d_in[7];
  const float* gb     = (const float*)d_in[8];
  const float* sW     = (const float*)d_in[9];
  const float* sb     = (const float*)d_in[10];
  const float* g0W0   = (const float*)d_in[11];
  const float* g0W1   = (const float*)d_in[12];
  const float* g0b    = (const float*)d_in[13];
  const float* g1W0   = (const float*)d_in[14];
  const float* g1W1   = (const float*)d_in[15];
  const float* g1b    = (const float*)d_in[16];
  const float* e1W    = (const float*)d_in[17];
  const float* e1b    = (const float*)d_in[18];
  const float* e2W    = (const float*)d_in[19];
  const float* e2b    = (const float*)d_in[20];
  float* out = (float*)d_out;
  float* ws  = (float*)d_ws;

  const int MP = 20096;
  size_t o = 0;
  unsigned short* hA = (unsigned short*)(ws + o); o += (size_t)NN*208;
  unsigned short* hB = (unsigned short*)(ws + o); o += (size_t)NN*208;
  unsigned short* Acat  = (unsigned short*)(ws + o); o += (size_t)MP*384;
  unsigned short* glcat = (unsigned short*)(ws + o); o += (size_t)MP*128;
  unsigned short* Wt0 = (unsigned short*)(ws + o); o += 147456;
  unsigned short* Wt1 = (unsigned short*)(ws + o); o += 36864;
  unsigned short* Bwt = (unsigned short*)(ws + o); o += 32768;
  unsigned short* Wfrag = (unsigned short*)(ws + o); o += 16384;
  float* Bfrag = ws + o; o += 2048;
  float* bP0   = ws + o; o += 384;
  float* bP1   = ws + o; o += 192;
  float* bias2 = ws + o; o += 256;
  float* Wc    = ws + o; o += 3072;
  float* bc    = ws + o; o += 16;
  float* stdev = ws + o; o += NN;
  float* means = ws + o; o += NN;
  float* xc    = ws + o; o += (size_t)NN*TT;
  float* deg   = ws + o; o += NN;            // deg, cnt, bnstats contiguous -> one memset
  int*   cnt   = (int*)(ws + o); o += NN;
  float* bnstats = ws + o; o += 8*1024;      // 8 layers x 16 buckets x 64 floats
  float* bnf0  = ws + o; o += 64;
  float* bnf1  = ws + o; o += 64;
  float* normb = ws + o; o += NE;
  int*   rowArr = (int*)(ws + o); o += NE;
  float* nrmArr = ws + o; o += NE;
  int*   rowptr = (int*)(ws + o); o += NN + 4;
  int*   woff   = (int*)(ws + o); o += NN;
  int*   bsum   = (int*)(ws + o); o += NBLK + 4;
  int*   bbase  = (int*)(ws + o); o += NBLK + 4;
  float* skipb  = (float*)hA;

  hipMemsetAsync(deg, 0, (2*NN + 8*1024)*sizeof(float), stream);
  k_instnorm<<<(NN+255)/256, 256, 0, stream>>>(x, xc, stdev, means);
  k_start2<<<((NN*TT*16)+255)/256, 256, 0, stream>>>(xc, startW, startb, hA);
  k_deg<<<(NE+255)/256, 256, 0, stream>>>(ei, ea, deg);
  k_dinv<<<(NN+255)/256, 256, 0, stream>>>(deg);
  k_normcount<<<(NE+255)/256, 256, 0, stream>>>(ei, ea, deg, normb, cnt);
  k_scanA<<<NBLK, 256, 0, stream>>>(cnt, bsum);
  k_scanB<<<1, 128, 0, stream>>>(bsum, bbase);
  k_scanC<<<NBLK, 256, 0, stream>>>(cnt, bbase, rowptr, woff);
  k_place<<<(NE+255)/256, 256, 0, stream>>>(normb, ei, woff, rowArr, nrmArr);
  k_prepall<<<1836, 256, 0, stream>>>(g0W0, g0W1, g0b, g1W0, g1W1, g1b,
      sW, sb, e1W, e1b, e2W, e2b, fW, fb, gW, gb,
      Wt0, bP0, Wt1, bP1, Bwt, bias2, Wc, bc, Wfrag, Bfrag);

  const int GB = 640;   // 2560 waves x 8 nodes
  // L0: hA -> hB
  k_gated5<1,13,12,false,true,true><<<GB,256,0,stream>>>(hA, hB, glcat+0,
      bnstats, bnstats+0*1024, Wfrag, Bfrag, 0, 0.f);
  // GCN0: fold stats0; BN(hB) -> Acat; gather; GEMM -> hA
  k_bnfold<<<1, 64, 0, stream>>>(bnstats+0*1024, bnf0);
  k_cvtbn2<<<((NN*192)+255)/256, 256, 0, stream>>>(hB, bnf0, 1.f/(NN*12.f), Acat, 384, 768);
  k_gather2<<<NN, 192, 0, stream>>>(Acat, 768, 384, 192, rowArr, nrmArr, rowptr, Acat);
  { dim3 g(MP/128, 384/64);
    k_gemm_bf16<true><<<g, 256, 0, stream>>>(Acat, Wt0, bP0, hA, NN, 384, 768); }
  // L1: hA -> hB
  k_gated5<2,12,10,false,true,true><<<GB,256,0,stream>>>(hA, hB, glcat+32,
      bnstats, bnstats+1*1024, Wfrag, Bfrag, 1, 0.f);
  // L2: hB -> hA
  k_gated5<1,10,9,true,true,true><<<GB,256,0,stream>>>(hB, hA, glcat+64,
      bnstats+1*1024, bnstats+2*1024, Wfrag, Bfrag, 2, 1.f/(NN*10.f));
  // L3: hA -> hB
  k_gated5<2,9,7,true,true,true><<<GB,256,0,stream>>>(hA, hB, glcat+96,
      bnstats+2*1024, bnstats+3*1024, Wfrag, Bfrag, 3, 1.f/(NN*9.f));
  // L4: hB -> hA
  k_gated5<1,7,6,true,true,true><<<GB,256,0,stream>>>(hB, hA, glcat+128,
      bnstats+3*1024, bnstats+4*1024, Wfrag, Bfrag, 4, 1.f/(NN*7.f));
  // GCN1: fold stats4; BN(hA) -> Acat; gather; GEMM -> hB
  k_bnfold<<<1, 64, 0, stream>>>(bnstats+4*1024, bnf1);
  k_cvtbn2<<<((NN*96)+255)/256, 256, 0, stream>>>(hA, bnf1, 1.f/(NN*6.f), Acat, 192, 384);
  k_gather2<<<NN, 128, 0, stream>>>(Acat, 384, 192, 96, rowArr, nrmArr, rowptr, Acat);
  { dim3 g(MP/128, 192/64);
    k_gemm_bf16<true><<<g, 256, 0, stream>>>(Acat, Wt1, bP1, hB, NN, 192, 384); }
  // L5: hB -> hA
  k_gated5<2,6,4,false,true,true><<<GB,256,0,stream>>>(hB, hA, glcat+160,
      bnstats, bnstats+5*1024, Wfrag, Bfrag, 5, 0.f);
  // L6: hA -> hB
  k_gated5<1,4,3,true,true,true><<<GB,256,0,stream>>>(hA, hB, glcat+192,
      bnstats+5*1024, bnstats+6*1024, Wfrag, Bfrag, 6, 1.f/(NN*4.f));
  // L7: hB -> (gl only)
  k_gated5<2,3,1,true,false,false><<<GB,256,0,stream>>>(hB, nullptr, glcat+224,
      bnstats+6*1024, bnstats+7*1024, Wfrag, Bfrag, 7, 1.f/(NN*3.f));

  // skip GEMM (fp32 out): skipb[N,256] = glcat @ Bwt^T + bias2
  { dim3 g(MP/128, 256/64);
    k_gemm_bf16<false><<<g, 256, 0, stream>>>(glcat, Bwt, bias2, skipb, NN, 256, 256); }
  k_final<<<((NN*12)+255)/256, 256, 0, stream>>>(skipb, Wc, bc, stdev, means, out);
}